// Round 10
// baseline (487.151 us; speedup 1.0000x reference)
//
#include <hip/hip_runtime.h>
#include <hip/hip_bf16.h>
#include <math.h>

#define EPSBN 1e-5f

using short8 = __attribute__((ext_vector_type(8))) short;
using f32x4  = __attribute__((ext_vector_type(4))) float;
using us4    = __attribute__((ext_vector_type(4))) unsigned short;

#define MFMA16(a, b, c) __builtin_amdgcn_mfma_f32_16x16x32_bf16(a, b, c, 0, 0, 0)

__device__ __forceinline__ float bf2f(unsigned short u) {
  unsigned int v = ((unsigned int)u) << 16;
  float f;
  __builtin_memcpy(&f, &v, 4);
  return f;
}
__device__ __forceinline__ unsigned short f2bf(float f) {
  __hip_bfloat16 h = __float2bfloat16(f);
  unsigned short u;
  __builtin_memcpy(&u, &h, 2);
  return u;
}
__device__ __forceinline__ float fast_sigmoid(float z) {
  return __builtin_amdgcn_rcpf(1.f + __expf(-z));
}
__device__ __forceinline__ float fast_tanh(float z) {
  float x2 = fminf(fmaxf(2.f * z, -30.f), 30.f);
  float e = __expf(x2);
  return (e - 1.f) * __builtin_amdgcn_rcpf(e + 1.f);
}
// async global->LDS, 16B per lane, dest = wave-uniform base + lane*16
__device__ __forceinline__ void stage16(const unsigned short* g, unsigned short* l) {
  __builtin_amdgcn_global_load_lds(
      (const __attribute__((address_space(1))) void*)g,
      (__attribute__((address_space(3))) void*)l, 16, 0, 0);
}

// ---------------- fused conv1 (3x3, CIN=1, COUT=64) + BN + 2x2 pool -> padded P1 ----------------
// coalesced output via LDS exchange: interior row = contiguous 16 KB run
__global__ __launch_bounds__(256) void conv1_pool(
    const float* __restrict__ in, const float* __restrict__ w,
    const float* __restrict__ bias, const float* __restrict__ sc,
    const float* __restrict__ of, const float* __restrict__ mn,
    const float* __restrict__ vr, unsigned short* __restrict__ out) {
  __shared__ float lds[4][258];
  __shared__ unsigned short obuf[128 * 64];
  const int blk = blockIdx.x;
  const int b = blk >> 4, y0 = blk & 15;
  const int tid = threadIdx.x;
  for (int i = tid; i < 4 * 258; i += 256) {
    int row = i / 258, c = i - row * 258;
    int iy = 2 * y0 - 1 + row, xx = c - 1;
    float v = 0.f;
    if ((unsigned)iy < 32u && (unsigned)xx < 256u)
      v = in[((b << 5) + iy) * 256 + xx];
    lds[row][c] = v;
  }
  __syncthreads();
  const int co = tid & 63, xg = tid >> 6;
  float w9[9];
  #pragma unroll
  for (int t = 0; t < 9; ++t) w9[t] = w[t * 64 + co];
  const float scale = sc[co] * rsqrtf(vr[co] + EPSBN);
  const float shift = of[co] - mn[co] * scale;
  const float bs = bias[co];
  for (int px = 0; px < 32; ++px) {
    const int xp = xg * 32 + px;
    float m = -1e30f;
    #pragma unroll
    for (int dy = 0; dy < 2; ++dy) {
      #pragma unroll
      for (int dx = 0; dx < 2; ++dx) {
        const int x = 2 * xp + dx;
        float acc = bs;
        #pragma unroll
        for (int r = 0; r < 3; ++r)
          #pragma unroll
          for (int cc = 0; cc < 3; ++cc)
            acc = fmaf(lds[dy + r][x + cc], w9[r * 3 + cc], acc);
        float v = fmaxf(acc, 0.f) * scale + shift;
        m = fmaxf(m, v);
      }
    }
    obuf[xp * 64 + co] = f2bf(m);
  }
  __syncthreads();
  unsigned short* orow = out + (((long)(b * 18 + y0 + 1) * 130 + 1) << 6);
  for (int i = tid; i < 1024; i += 256)
    *(short8*)(orow + i * 8) = *(const short8*)(obuf + i * 8);
}

// ---------------- 2x2 maxpool -> PADDED output, short8 channel-vectorized ----------------
template<int C, int H2, int W2>
__global__ __launch_bounds__(256) void maxpool_pad_vec(
    const unsigned short* __restrict__ in, unsigned short* __restrict__ out) {
  constexpr int W2P = W2 + 2, H2P = H2 + 2, C8 = C / 8;
  const long total = (long)64 * H2P * W2P * C8;
  long i = (long)blockIdx.x * 256 + threadIdx.x;
  if (i >= total) return;
  const int c8 = (int)(i % C8);
  long r = i / C8;
  const int xp = (int)(r % W2P); r /= W2P;
  const int yp = (int)(r % H2P);
  const int b = (int)(r / H2P);
  short8 res = {};
  if (yp >= 1 && yp <= H2 && xp >= 1 && xp <= W2) {
    const long rs = (long)(2 * W2) * C;
    const unsigned short* p0 =
        in + (((long)b * (2 * H2) + (yp - 1) * 2) * (2 * W2) + (xp - 1) * 2) * C + c8 * 8;
    short8 v00 = *(const short8*)(p0);
    short8 v01 = *(const short8*)(p0 + C);
    short8 v10 = *(const short8*)(p0 + rs);
    short8 v11 = *(const short8*)(p0 + rs + C);
    #pragma unroll
    for (int e = 0; e < 8; ++e) {
      float f0 = bf2f((unsigned short)v00[e]), f1 = bf2f((unsigned short)v01[e]);
      float f2 = bf2f((unsigned short)v10[e]), f3 = bf2f((unsigned short)v11[e]);
      float mx = fmaxf(fmaxf(f0, f1), fmaxf(f2, f3));
      unsigned short uu;
      if (mx == f0) uu = (unsigned short)v00[e];
      else if (mx == f1) uu = (unsigned short)v01[e];
      else if (mx == f2) uu = (unsigned short)v10[e];
      else uu = (unsigned short)v11[e];
      res[e] = (short)uu;
    }
  }
  *(short8*)(out + (((long)b * H2P + yp) * W2P + xp) * C + c8 * 8) = res;
}

// ---------------- merged weight transposes: fp32 [K][N] -> bf16 [N][K], 9 at once ----------------
struct TAll {
  const float* src[9];
  unsigned short* dst[9];
  int K[9];
  int N[9];
};
__global__ __launch_bounds__(256) void transpose_multi(TAll P) {
  const int z = blockIdx.z;
  const int K = P.K[z], N = P.N[z];
  const int k0 = blockIdx.x * 32, n0 = blockIdx.y * 32;
  if (k0 >= K || n0 >= N) return;
  __shared__ float T[32][33];
  const float* in = P.src[z];
  unsigned short* out = P.dst[z];
  const int tid = threadIdx.x;
  const int r = tid >> 3, c4 = (tid & 7) * 4;
  if (n0 + 32 <= N) {
    float4 v = *(const float4*)(in + (long)(k0 + r) * N + n0 + c4);
    T[r][c4 + 0] = v.x; T[r][c4 + 1] = v.y; T[r][c4 + 2] = v.z; T[r][c4 + 3] = v.w;
  } else {
    #pragma unroll
    for (int i = 0; i < 4; ++i) {
      int col = n0 + c4 + i;
      T[r][c4 + i] = (col < N) ? in[(long)(k0 + r) * N + col] : 0.f;
    }
  }
  __syncthreads();
  if (n0 + r < N) {
    us4 o;
    #pragma unroll
    for (int i = 0; i < 4; ++i) o[i] = f2bf(T[c4 + i][r]);
    *(us4*)(out + (long)(n0 + r) * K + k0 + c4) = o;
  }
}

// ---------------- merged zero init: 4 regions, grid-stride ----------------
__global__ __launch_bounds__(256) void zero_multi(
    float* p0, long n0, float* p1, long n1, float* p2, long n2, float* p3, long n3) {
  const long i0 = (long)blockIdx.x * 256 + threadIdx.x;
  const long st = (long)gridDim.x * 256;
  for (long j = i0; j < n0; j += st) p0[j] = 0.f;
  for (long j = i0; j < n1; j += st) p1[j] = 0.f;
  for (long j = i0; j < n2; j += st) p2[j] = 0.f;
  for (long j = i0; j < n3; j += st) p3[j] = 0.f;
}

// ---------------- 2-phase pipelined implicit-GEMM conv, XCD-swizzled 1-D grid ----------------
template<int CIN, int COUT, int H, int W, int OUTPAD, int NBM, int NBN>
__global__ __launch_bounds__(256) void conv_mfma128(
    const unsigned short* __restrict__ act, const unsigned short* __restrict__ wT,
    const float* __restrict__ bias, const float* __restrict__ sc,
    const float* __restrict__ of, const float* __restrict__ mn,
    const float* __restrict__ vr, unsigned short* __restrict__ out) {
  constexpr int K9 = 9 * CIN;
  constexpr int HW = H * W;
  constexpr int WP = W + 2;
  constexpr int NK = K9 / 32;
  constexpr int NWG = NBM * NBN;
  constexpr int CSH = (CIN == 64) ? 1 : (CIN == 128) ? 2 : 3;
  constexpr int CMSK = (1 << CSH) - 1;
  __shared__ unsigned short As[2][4096];
  __shared__ unsigned short Bs[2][4096];
  const int tid = threadIdx.x;
  const int lane = tid & 63, wave = tid >> 6;
  const int wzw = blockIdx.x;
  const int logical = (wzw & 7) * (NWG >> 3) + (wzw >> 3);
  const int m0 = (logical % NBM) * 128, n0 = (logical / NBM) * 128;
  const int r0 = tid >> 2, seg = tid & 3;
  const int segp = (seg ^ (r0 & 3)) << 3;
  long pa0, pa1;
  {
    const int m = m0 + r0;
    const int b = m / HW, rem = m % HW;
    const int y = rem / W, x = rem % W;
    pa0 = (((long)b * (H + 2) + y) * WP + x) * CIN + segp;
  }
  {
    const int m = m0 + r0 + 64;
    const int b = m / HW, rem = m % HW;
    const int y = rem / W, x = rem % W;
    pa1 = (((long)b * (H + 2) + y) * WP + x) * CIN + segp;
  }
  const long pb0 = (long)(n0 + r0) * K9 + segp;
  const long pb1 = (long)(n0 + r0 + 64) * K9 + segp;
  const int swz = ((lane >> 4) ^ (lane & 3)) << 3;
  const int arow0 = (wave >> 1) * 64 + (lane & 15);
  const int brow0 = (wave & 1) * 64 + (lane & 15);
  f32x4 acc[4][4] = {};

  auto stage_tile = [&](int ks, int buf) {
    const int tap = ks >> CSH;
    const int cib = (ks & CMSK) << 5;
    const int ty = (tap * 86) >> 8;          // tap/3 for tap<9
    const int tx = tap - ty * 3;
    const long ka = (long)(ty * WP + tx) * CIN + cib;
    const long kb = (long)ks << 5;
    unsigned short* aw = &As[buf][wave * 512];
    unsigned short* bw = &Bs[buf][wave * 512];
    stage16(act + pa0 + ka, aw);
    stage16(act + pa1 + ka, aw + 2048);
    stage16(wT + pb0 + kb, bw);
    stage16(wT + pb1 + kb, bw + 2048);
  };

  stage_tile(0, 0);
  #pragma unroll 1
  for (int ks = 0; ks < NK; ++ks) {
    const int buf = ks & 1;
    if (ks + 1 < NK) {
      stage_tile(ks + 1, buf ^ 1);
      asm volatile("s_waitcnt vmcnt(4)" ::: "memory");
    } else {
      asm volatile("s_waitcnt vmcnt(0)" ::: "memory");
    }
    __builtin_amdgcn_s_barrier();
    __builtin_amdgcn_sched_barrier(0);
    short8 a[4], b[4];
    #pragma unroll
    for (int i = 0; i < 4; ++i)
      a[i] = *(const short8*)(&As[buf][(arow0 + i * 16) * 32 + swz]);
    #pragma unroll
    for (int j = 0; j < 4; ++j)
      b[j] = *(const short8*)(&Bs[buf][(brow0 + j * 16) * 32 + swz]);
    #pragma unroll
    for (int i = 0; i < 4; ++i)
      #pragma unroll
      for (int j = 0; j < 4; ++j)
        acc[i][j] = MFMA16(a[i], b[j], acc[i][j]);
    __builtin_amdgcn_s_barrier();
    __builtin_amdgcn_sched_barrier(0);
  }

  float scl[4], shf[4], bsv[4];
  #pragma unroll
  for (int j = 0; j < 4; ++j) {
    const int col = n0 + (wave & 1) * 64 + j * 16 + (lane & 15);
    scl[j] = sc[col] * rsqrtf(vr[col] + EPSBN);
    shf[j] = of[col] - mn[col] * scl[j];
    bsv[j] = bias[col];
  }
  #pragma unroll
  for (int i = 0; i < 4; ++i) {
    #pragma unroll
    for (int rr = 0; rr < 4; ++rr) {
      const int m = m0 + (wave >> 1) * 64 + i * 16 + (lane >> 4) * 4 + rr;
      const int b = m / HW, rem = m % HW;
      const int y = rem / W, x = rem % W;
      long obase;
      if (OUTPAD) obase = (((long)b * (H + 2) + y + 1) * WP + x + 1) * COUT;
      else        obase = (((long)b * H + y) * W + x) * COUT;
      const int colb = n0 + (wave & 1) * 64 + (lane & 15);
      #pragma unroll
      for (int j = 0; j < 4; ++j) {
        const float v = fmaxf(acc[i][j][rr] + bsv[j], 0.f) * scl[j] + shf[j];
        out[obase + colb + j * 16] = f2bf(v);
      }
    }
  }
}

// ---------------- fused 2-dir 2-phase GEMM, XCD-swizzled: xw = gather(x) @ WiT^T + b ----------------
__global__ __launch_bounds__(256) void gemm_xw2(
    const unsigned short* __restrict__ src,
    const unsigned short* __restrict__ WiTF, const unsigned short* __restrict__ WiTB,
    const float* __restrict__ bF, const float* __restrict__ bB,
    float* __restrict__ xwFp, float* __restrict__ xwBp) {
  __shared__ unsigned short As[2][4096];
  __shared__ unsigned short Bs[2][4096];
  const int rev = blockIdx.z;
  const unsigned short* WiT = rev ? WiTB : WiTF;
  const float* bvec = rev ? bB : bF;
  float* xw = rev ? xwBp : xwFp;
  const int tid = threadIdx.x;
  const int lane = tid & 63, wave = tid >> 6;
  const int wzw = blockIdx.x;                       // 0..255
  const int logical = (wzw & 7) * 32 + (wzw >> 3);  // bijective, chunks of 32/XCD
  const int m0 = (logical & 15) * 128, n0 = (logical >> 4) * 128;
  const int r0 = tid >> 2, seg = tid & 3;
  const int segp = (seg ^ (r0 & 3)) << 3;
  long pa0, pa1;
  {
    const int r = m0 + r0;
    const int t = r >> 6, bb = r & 63;
    const int tt = rev ? 31 - t : t;
    pa0 = (long)bb * 65536 + (long)tt * 2048 + segp;
  }
  {
    const int r = m0 + r0 + 64;
    const int t = r >> 6, bb = r & 63;
    const int tt = rev ? 31 - t : t;
    pa1 = (long)bb * 65536 + (long)tt * 2048 + segp;
  }
  const long pb0 = (long)(n0 + r0) * 2048 + segp;
  const long pb1 = (long)(n0 + r0 + 64) * 2048 + segp;
  const int swz = ((lane >> 4) ^ (lane & 3)) << 3;
  const int arow0 = (wave >> 1) * 64 + (lane & 15);
  const int brow0 = (wave & 1) * 64 + (lane & 15);
  f32x4 acc[4][4] = {};

  auto stage_tile = [&](int ks, int buf) {
    const long k0 = (long)ks << 5;
    unsigned short* aw = &As[buf][wave * 512];
    unsigned short* bw = &Bs[buf][wave * 512];
    stage16(src + pa0 + k0, aw);
    stage16(src + pa1 + k0, aw + 2048);
    stage16(WiT + pb0 + k0, bw);
    stage16(WiT + pb1 + k0, bw + 2048);
  };

  stage_tile(0, 0);
  #pragma unroll 1
  for (int ks = 0; ks < 64; ++ks) {
    const int buf = ks & 1;
    if (ks + 1 < 64) {
      stage_tile(ks + 1, buf ^ 1);
      asm volatile("s_waitcnt vmcnt(4)" ::: "memory");
    } else {
      asm volatile("s_waitcnt vmcnt(0)" ::: "memory");
    }
    __builtin_amdgcn_s_barrier();
    __builtin_amdgcn_sched_barrier(0);
    short8 a[4], b[4];
    #pragma unroll
    for (int i = 0; i < 4; ++i)
      a[i] = *(const short8*)(&As[buf][(arow0 + i * 16) * 32 + swz]);
    #pragma unroll
    for (int j = 0; j < 4; ++j)
      b[j] = *(const short8*)(&Bs[buf][(brow0 + j * 16) * 32 + swz]);
    #pragma unroll
    for (int i = 0; i < 4; ++i)
      #pragma unroll
      for (int j = 0; j < 4; ++j)
        acc[i][j] = MFMA16(a[i], b[j], acc[i][j]);
    __builtin_amdgcn_s_barrier();
    __builtin_amdgcn_sched_barrier(0);
  }

  float bsv[4];
  #pragma unroll
  for (int j = 0; j < 4; ++j)
    bsv[j] = bvec[n0 + (wave & 1) * 64 + j * 16 + (lane & 15)];
  #pragma unroll
  for (int i = 0; i < 4; ++i) {
    #pragma unroll
    for (int rr = 0; rr < 4; ++rr) {
      const int row = m0 + (wave >> 1) * 64 + i * 16 + (lane >> 4) * 4 + rr;
      const int colb = n0 + (wave & 1) * 64 + (lane & 15);
      #pragma unroll
      for (int j = 0; j < 4; ++j)
        xw[(long)row * 2048 + colb + j * 16] = acc[i][j][rr] + bsv[j];
    }
  }
}

// ---------------- persistent bidirectional LSTM; relaxed poll + one-time acquire fence ----------------
__global__ __launch_bounds__(256) void lstm_persist(
    const unsigned short* __restrict__ WhTF, const unsigned short* __restrict__ WhTB,
    const float* __restrict__ xwF, const float* __restrict__ xwB,
    unsigned short* __restrict__ hsF, unsigned short* __restrict__ hsB,
    int* __restrict__ bar) {
  __shared__ unsigned short Whs[64 * 512];
  __shared__ unsigned short Hs[64 * 512];
  __shared__ float Zs[4 * 64 * 16];
  const int bid = blockIdx.x;
  const int dir = bid >> 5;
  const int nb = bid & 31;
  const int u0 = nb * 16;
  const unsigned short* WhT = dir ? WhTB : WhTF;
  const float* xw = dir ? xwB : xwF;
  unsigned short* hs = dir ? hsB : hsF;
  int* flagbase = bar + dir * 32 * 16;
  int* myflag = flagbase + nb * 16;
  const int tid = threadIdx.x;
  const int lane = tid & 63, wave = tid >> 6;
  const int lr = lane & 15, lk = lane >> 4;
  const int mp = wave >> 1, gp = wave & 1;

  #pragma unroll
  for (int i = 0; i < 16; ++i) {
    const int G = i * 256 + tid;
    const int row = G >> 6, g8 = G & 63;
    const int g = row >> 4, u = row & 15;
    short8 v = *(const short8*)(WhT + ((long)(g * 512 + u0 + u) << 9) + g8 * 8);
    *(short8*)(Whs + row * 512 + ((g8 ^ (row & 7)) << 3)) = v;
  }

  const int prow = tid >> 2;
  const int pu4 = (tid & 3) * 4;
  float c4[4] = {0.f, 0.f, 0.f, 0.f};
  float4 xq[4];
  #pragma unroll
  for (int g = 0; g < 4; ++g)
    xq[g] = *(const float4*)(xw + (long)prow * 2048 + g * 512 + u0 + pu4);

  for (int t = 0; t < 32; ++t) {
    const unsigned short* hsrc = hs + (long)t * 32768;
    #pragma unroll
    for (int i = 0; i < 16; ++i) {
      const int G = i * 256 + tid;
      const int row = G >> 6, g8 = G & 63;
      short8 v = *(const short8*)(hsrc + G * 8);
      *(short8*)(Hs + row * 512 + ((g8 ^ (row & 7)) << 3)) = v;
    }
    __syncthreads();

    f32x4 acc[2][2] = {};
    #pragma unroll
    for (int kk = 0; kk < 16; ++kk) {
      const int sw = ((lk + kk * 4) ^ (lr & 7)) << 3;
      short8 a0 = *(const short8*)(Hs + (mp * 32 + lr) * 512 + sw);
      short8 a1 = *(const short8*)(Hs + (mp * 32 + 16 + lr) * 512 + sw);
      short8 b0 = *(const short8*)(Whs + (gp * 32 + lr) * 512 + sw);
      short8 b1 = *(const short8*)(Whs + (gp * 32 + 16 + lr) * 512 + sw);
      acc[0][0] = MFMA16(a0, b0, acc[0][0]);
      acc[0][1] = MFMA16(a0, b1, acc[0][1]);
      acc[1][0] = MFMA16(a1, b0, acc[1][0]);
      acc[1][1] = MFMA16(a1, b1, acc[1][1]);
    }

    #pragma unroll
    for (int im = 0; im < 2; ++im) {
      const int rowb = (mp * 2 + im) * 16 + lk * 4;
      #pragma unroll
      for (int ig = 0; ig < 2; ++ig) {
        const int g = gp * 2 + ig;
        #pragma unroll
        for (int r = 0; r < 4; ++r)
          Zs[g * 1024 + (rowb + r) * 16 + lr] = acc[im][ig][r];
      }
    }
    __syncthreads();

    {
      float4 zi = *(const float4*)(Zs + tid * 4);
      float4 zf = *(const float4*)(Zs + 1024 + tid * 4);
      float4 zg = *(const float4*)(Zs + 2048 + tid * 4);
      float4 zo = *(const float4*)(Zs + 3072 + tid * 4);
      const float* pzi = (const float*)&zi;
      const float* pzf = (const float*)&zf;
      const float* pzg = (const float*)&zg;
      const float* pzo = (const float*)&zo;
      us4 hv;
      #pragma unroll
      for (int r = 0; r < 4; ++r) {
        float ii = fast_sigmoid(pzi[r] + ((const float*)&xq[0])[r]);
        float ff = fast_sigmoid(pzf[r] + ((const float*)&xq[1])[r]);
        float gg = fast_tanh(pzg[r] + ((const float*)&xq[2])[r]);
        float oo = fast_sigmoid(pzo[r] + ((const float*)&xq[3])[r]);
        c4[r] = ff * c4[r] + ii * gg;
        hv[r] = f2bf(oo * fast_tanh(c4[r]));
      }
      *(us4*)(hs + (long)(t + 1) * 32768 + prow * 512 + u0 + pu4) = hv;
    }

    if (t < 31) {
      float4 xqn[4];
      #pragma unroll
      for (int g = 0; g < 4; ++g)
        xqn[g] = *(const float4*)(xw + (long)((t + 1) * 64 + prow) * 2048 + g * 512 + u0 + pu4);
      __syncthreads();
      if (tid < 64) {
        if (tid == 0)
          __hip_atomic_store(myflag, t + 1, __ATOMIC_RELEASE, __HIP_MEMORY_SCOPE_AGENT);
        int v;
        do {
          v = __hip_atomic_load(flagbase + (tid & 31) * 16,
                                __ATOMIC_RELAXED, __HIP_MEMORY_SCOPE_AGENT);
        } while (__any(v < t + 1));
      }
      __syncthreads();
      __builtin_amdgcn_fence(__ATOMIC_ACQUIRE, "agent");
      #pragma unroll
      for (int g = 0; g < 4; ++g) xq[g] = xqn[g];
    }
  }
}

// ---------------- MFMA FC (M=128,N=80,K=1024) + fused log_softmax ----------------
__global__ __launch_bounds__(256) void fc_mfma_ls(
    const unsigned short* __restrict__ hsF, const unsigned short* __restrict__ hsB,
    const unsigned short* __restrict__ WT, const float* __restrict__ bias,
    float* __restrict__ out) {
  __shared__ unsigned short As_[128 * 32];
  __shared__ unsigned short Bs_[80 * 32];
  __shared__ float zbuf[128][81];
  __shared__ float rmax[128];
  __shared__ float rlse[128];
  const int tid = threadIdx.x;
  const int lane = tid & 63, wave = tid >> 6;
  const int m0 = blockIdx.x * 128;
  const int r0 = tid >> 2, seg = tid & 3;
  const int segp = (seg ^ (r0 & 3)) << 3;
  const int swz = ((lane >> 4) ^ (lane & 3)) << 3;
  f32x4 acc[2][5] = {};

  int bA0, tA0, bA1, tA1;
  { int r = m0 + r0;      bA0 = r >> 5; tA0 = r & 31; }
  { int r = m0 + r0 + 64; bA1 = r >> 5; tA1 = r & 31; }

  #pragma unroll 1
  for (int k0 = 0; k0 < 1024; k0 += 32) {
    const unsigned short* src = (k0 < 512) ? hsF : hsB;
    const int koff = k0 & 511;
    stage16(src + (long)(tA0 + 1) * 32768 + bA0 * 512 + koff + segp, As_ + wave * 512);
    stage16(src + (long)(tA1 + 1) * 32768 + bA1 * 512 + koff + segp, As_ + wave * 512 + 2048);
    {
      int G = tid;
      #pragma unroll
      for (int it = 0; it < 2; ++it, G += 256) {
        int rn = G >> 2, sg = G & 3;
        if (rn < 80) {
          short8 v = *(const short8*)(WT + (long)rn * 1024 + k0 + sg * 8);
          *(short8*)(Bs_ + rn * 32 + ((sg ^ (rn & 3)) << 3)) = v;
        }
      }
    }
    __syncthreads();
    short8 a[2], bfrag[5];
    #pragma unroll
    for (int i = 0; i < 2; ++i)
      a[i] = *(const short8*)(As_ + (wave * 32 + i * 16 + (lane & 15)) * 32 + swz);
    #pragma unroll
    for (int j = 0; j < 5; ++j)
      bfrag[j] = *(const short8*)(Bs_ + (j * 16 + (lane & 15)) * 32 + swz);
    #pragma unroll
    for (int i = 0; i < 2; ++i)
      #pragma unroll
      for (int j = 0; j < 5; ++j)
        acc[i][j] = MFMA16(a[i], bfrag[j], acc[i][j]);
    __syncthreads();
  }

  float bsv[5];
  #pragma unroll
  for (int j = 0; j < 5; ++j) bsv[j] = bias[j * 16 + (lane & 15)];
  #pragma unroll
  for (int i = 0; i < 2; ++i)
    #pragma unroll
    for (int j = 0; j < 5; ++j)
      #pragma unroll
      for (int rr = 0; rr < 4; ++rr)
        zbuf[wave * 32 + i * 16 + (lane >> 4) * 4 + rr][j * 16 + (lane & 15)] =
            acc[i][j][rr] + bsv[j];
  __syncthreads();

  if (tid < 128) {
    float mx = -1e30f;
    for (int j = 0; j < 80; ++j) mx = fmaxf(mx, zbuf[tid][j]);
    float s = 0.f;
    for (int j = 0; j < 80; ++j) s += __expf(zbuf[tid][j] - mx);
    rmax[tid] = mx;
    rlse[tid] = logf(s);
  }
  __syncthreads();

  for (int idx = tid; idx < 128 * 80; idx += 256) {
    const int row = idx / 80, j = idx - row * 80;
    out[(long)m0 * 80 + idx] = zbuf[row][j] - rmax[row] - rlse[row];
  }
}

extern "C" void kernel_launch(void* const* d_in, const int* in_sizes, int n_in,
                              void* d_out, int out_size, void* d_ws, size_t ws_size,
                              hipStream_t stream) {
  const float* x  = (const float*)d_in[0];
  const float* k1 = (const float*)d_in[1];  const float* b1 = (const float*)d_in[2];
  const float* s1 = (const float*)d_in[3];  const float* o1 = (const float*)d_in[4];
  const float* m1 = (const float*)d_in[5];  const float* v1 = (const float*)d_in[6];
  const float* k2 = (const float*)d_in[7];  const float* b2 = (const float*)d_in[8];
  const float* s2 = (const float*)d_in[9];  const float* o2 = (const float*)d_in[10];
  const float* m2 = (const float*)d_in[11]; const float* v2 = (const float*)d_in[12];
  const float* k3 = (const float*)d_in[13]; const float* b3 = (const float*)d_in[14];
  const float* s3 = (const float*)d_in[15]; const float* o3 = (const float*)d_in[16];
  const float* m3 = (const float*)d_in[17]; const float* v3 = (const float*)d_in[18];
  const float* k4 = (const float*)d_in[19]; const float* b4 = (const float*)d_in[20];
  const float* s4 = (const float*)d_in[21]; const float* o4 = (const float*)d_in[22];
  const float* m4 = (const float*)d_in[23]; const float* v4 = (const float*)d_in[24];
  const float* k5 = (const float*)d_in[25]; const float* b5 = (const float*)d_in[26];
  const float* s5 = (const float*)d_in[27]; const float* o5 = (const float*)d_in[28];
  const float* m5 = (const float*)d_in[29]; const float* v5 = (const float*)d_in[30];
  const float* fwWi = (const float*)d_in[31];
  const float* fwWh = (const float*)d_in[32];
  const float* fwb  = (const float*)d_in[33];
  const float* bwWi = (const float*)d_in[34];
  const float* bwWh = (const float*)d_in[35];
  const float* bwb  = (const float*)d_in[36];
  const float* fcW  = (const float*)d_in[37];
  const float* fcb  = (const float*)d_in[38];

  char* wsb = (char*)d_ws;
  unsigned short* REG_A = (unsigned short*)(wsb);                  // 33,554,432 B
  unsigned short* REG_P = (unsigned short*)(wsb + 33554432);       // 19,169,280 B
  unsigned short* C4    = (unsigned short*)(wsb + 52723712);       //  6,684,672 B
  unsigned short* wT2   = (unsigned short*)(wsb + 59408384);       //    147,456 B
  unsigned short* wT3   = (unsigned short*)(wsb + 59555840);       //    589,824 B
  unsigned short* wT4   = (unsigned short*)(wsb + 60145664);       //  1,179,648 B
  unsigned short* wT5   = (unsigned short*)(wsb + 61325312);       //  2,359,296 B
  unsigned short* WiTF  = (unsigned short*)(wsb + 63684608);       //  8,388,608 B
  unsigned short* WiTB  = (unsigned short*)(wsb + 72073216);       //  8,388,608 B
  unsigned short* WhTF  = (unsigned short*)(wsb + 80461824);       //  2,097,152 B
  unsigned short* WhTB  = (unsigned short*)(wsb + 82558976);       //  2,097,152 B
  unsigned short* WTfc  = (unsigned short*)(wsb + 84656128);       //    163,840 B
  float* xwF = (float*)(wsb + 84819968);                           // 16,777,216 B
  float* xwB = (float*)(wsb + 101597184);                          // 16,777,216 B
  int*   bar = (int*)(wsb + 118374400);                            //      4,096 B
  unsigned short* hsF = (unsigned short*)(wsb + 118378496);        //  2,162,688 B
  unsigned short* hsB = (unsigned short*)(wsb + 120541184);        //  2,162,688 B

  // zeros: {bar+hsF slab0}, {hsB slab0}, {C4 full}, {P1 full}
  zero_multi<<<2048, 256, 0, stream>>>(
      (float*)(wsb + 118374400), 17408,
      (float*)(wsb + 120541184), 16384,
      (float*)(wsb + 52723712), 1671168,
      (float*)(wsb + 33554432), 4792320);

  // all weight transposes in one dispatch (incl. FC ragged-N)
  TAll tp;
  tp.src[0] = k2; tp.dst[0] = wT2; tp.K[0] = 576;  tp.N[0] = 128;
  tp.src[1] = k3; tp.dst[1] = wT3; tp.K[1] = 1152; tp.N[1] = 256;
  tp.src[2] = k4; tp.dst[2] = wT4; tp.K[2] = 2304; tp.N[2] = 256;
  tp.src[3] = k5; tp.dst[3] = wT5; tp.K[3] = 2304; tp.N[3] = 512;
  tp.src[4] = fwWi + 4194304; tp.dst[4] = WiTF; tp.K[4] = 2048; tp.N[4] = 2048;
  tp.src[5] = bwWi + 4194304; tp.dst[5] = WiTB; tp.K[5] = 2048; tp.N[5] = 2048;
  tp.src[6] = fwWh + 1048576; tp.dst[6] = WhTF; tp.K[6] = 512;  tp.N[6] = 2048;
  tp.src[7] = bwWh + 1048576; tp.dst[7] = WhTB; tp.K[7] = 512;  tp.N[7] = 2048;
  tp.src[8] = fcW; tp.dst[8] = WTfc; tp.K[8] = 1024; tp.N[8] = 80;
  transpose_multi<<<dim3(72, 64, 9), 256, 0, stream>>>(tp);

  // fused conv1+pool1 -> P1 padded [64,18,130,64]
  conv1_pool<<<1024, 256, 0, stream>>>(x, k1, b1, s1, o1, m1, v1, REG_P);

  // conv2: P1 -> C2 [64,16,128,128]
  conv_mfma128<64, 128, 16, 128, 0, 1024, 1><<<1024, 256, 0, stream>>>(
      REG_P, wT2, b2, s2, o2, m2, v2, REG_A);
  maxpool_pad_vec<128, 8, 64><<<2640, 256, 0, stream>>>(REG_A, REG_P);

  // conv3: P2 -> C3 [64,8,64,256]
  conv_mfma128<128, 256, 8, 64, 0, 256, 2><<<512, 256, 0, stream>>>(
      REG_P, wT3, b3, s3, o3, m3, v3, REG_A);
  maxpool_pad_vec<256, 4, 32><<<1632, 256, 0, stream>>>(REG_A, REG_P);

  // conv4: P3 -> C4 PADDED [64,6,34,256]
  conv_mfma128<256, 256, 4, 32, 1, 64, 2><<<128, 256, 0, stream>>>(
      REG_P, wT4, b4, s4, o4, m4, v4, C4);

  // conv5: C4 -> C5 [64,4,32,512]
  conv_mfma128<256, 512, 4, 32, 0, 64, 4><<<256, 256, 0, stream>>>(
      C4, wT5, b5, s5, o5, m5, v5, REG_A);

  // xw precompute, both directions fused (layer 1 only), XCD-swizzled
  gemm_xw2<<<dim3(256, 1, 2), 256, 0, stream>>>(
      REG_A, WiTF, WiTB, fwb + 2048, bwb + 2048, xwF, xwB);

  // all 32 LSTM steps, both directions, single launch
  lstm_persist<<<64, 256, 0, stream>>>(WhTF, WhTB, xwF, xwB, hsF, hsB, bar);

  // FC + log_softmax
  fc_mfma_ls<<<16, 256, 0, stream>>>(hsF, hsB, WTfc, fcb, (float*)d_out);
}

// Round 11
// 464.440 us; speedup vs baseline: 1.0489x; 1.0489x over previous
//
#include <hip/hip_runtime.h>
#include <hip/hip_bf16.h>
#include <math.h>

#define EPSBN 1e-5f

using short8 = __attribute__((ext_vector_type(8))) short;
using f32x4  = __attribute__((ext_vector_type(4))) float;
using us4    = __attribute__((ext_vector_type(4))) unsigned short;

#define MFMA16(a, b, c) __builtin_amdgcn_mfma_f32_16x16x32_bf16(a, b, c, 0, 0, 0)

__device__ __forceinline__ float bf2f(unsigned short u) {
  unsigned int v = ((unsigned int)u) << 16;
  float f;
  __builtin_memcpy(&f, &v, 4);
  return f;
}
__device__ __forceinline__ unsigned short f2bf(float f) {
  __hip_bfloat16 h = __float2bfloat16(f);
  unsigned short u;
  __builtin_memcpy(&u, &h, 2);
  return u;
}
__device__ __forceinline__ float fast_sigmoid(float z) {
  return __builtin_amdgcn_rcpf(1.f + __expf(-z));
}
__device__ __forceinline__ float fast_tanh(float z) {
  float x2 = fminf(fmaxf(2.f * z, -30.f), 30.f);
  float e = __expf(x2);
  return (e - 1.f) * __builtin_amdgcn_rcpf(e + 1.f);
}
// async global->LDS, 16B per lane, dest = wave-uniform base + lane*16
__device__ __forceinline__ void stage16(const unsigned short* g, unsigned short* l) {
  __builtin_amdgcn_global_load_lds(
      (const __attribute__((address_space(1))) void*)g,
      (__attribute__((address_space(3))) void*)l, 16, 0, 0);
}

// ---------------- fused conv1 (3x3, CIN=1, COUT=64) + BN + 2x2 pool -> padded P1 ----------------
// coalesced output via LDS exchange: interior row = contiguous 16 KB run
__global__ __launch_bounds__(256) void conv1_pool(
    const float* __restrict__ in, const float* __restrict__ w,
    const float* __restrict__ bias, const float* __restrict__ sc,
    const float* __restrict__ of, const float* __restrict__ mn,
    const float* __restrict__ vr, unsigned short* __restrict__ out) {
  __shared__ float lds[4][258];
  __shared__ unsigned short obuf[128 * 64];
  const int blk = blockIdx.x;
  const int b = blk >> 4, y0 = blk & 15;
  const int tid = threadIdx.x;
  for (int i = tid; i < 4 * 258; i += 256) {
    int row = i / 258, c = i - row * 258;
    int iy = 2 * y0 - 1 + row, xx = c - 1;
    float v = 0.f;
    if ((unsigned)iy < 32u && (unsigned)xx < 256u)
      v = in[((b << 5) + iy) * 256 + xx];
    lds[row][c] = v;
  }
  __syncthreads();
  const int co = tid & 63, xg = tid >> 6;
  float w9[9];
  #pragma unroll
  for (int t = 0; t < 9; ++t) w9[t] = w[t * 64 + co];
  const float scale = sc[co] * rsqrtf(vr[co] + EPSBN);
  const float shift = of[co] - mn[co] * scale;
  const float bs = bias[co];
  for (int px = 0; px < 32; ++px) {
    const int xp = xg * 32 + px;
    float m = -1e30f;
    #pragma unroll
    for (int dy = 0; dy < 2; ++dy) {
      #pragma unroll
      for (int dx = 0; dx < 2; ++dx) {
        const int x = 2 * xp + dx;
        float acc = bs;
        #pragma unroll
        for (int r = 0; r < 3; ++r)
          #pragma unroll
          for (int cc = 0; cc < 3; ++cc)
            acc = fmaf(lds[dy + r][x + cc], w9[r * 3 + cc], acc);
        float v = fmaxf(acc, 0.f) * scale + shift;
        m = fmaxf(m, v);
      }
    }
    obuf[xp * 64 + co] = f2bf(m);
  }
  __syncthreads();
  unsigned short* orow = out + (((long)(b * 18 + y0 + 1) * 130 + 1) << 6);
  for (int i = tid; i < 1024; i += 256)
    *(short8*)(orow + i * 8) = *(const short8*)(obuf + i * 8);
}

// ---------------- 2x2 maxpool -> PADDED output, short8 channel-vectorized ----------------
template<int C, int H2, int W2>
__global__ __launch_bounds__(256) void maxpool_pad_vec(
    const unsigned short* __restrict__ in, unsigned short* __restrict__ out) {
  constexpr int W2P = W2 + 2, H2P = H2 + 2, C8 = C / 8;
  const long total = (long)64 * H2P * W2P * C8;
  long i = (long)blockIdx.x * 256 + threadIdx.x;
  if (i >= total) return;
  const int c8 = (int)(i % C8);
  long r = i / C8;
  const int xp = (int)(r % W2P); r /= W2P;
  const int yp = (int)(r % H2P);
  const int b = (int)(r / H2P);
  short8 res = {};
  if (yp >= 1 && yp <= H2 && xp >= 1 && xp <= W2) {
    const long rs = (long)(2 * W2) * C;
    const unsigned short* p0 =
        in + (((long)b * (2 * H2) + (yp - 1) * 2) * (2 * W2) + (xp - 1) * 2) * C + c8 * 8;
    short8 v00 = *(const short8*)(p0);
    short8 v01 = *(const short8*)(p0 + C);
    short8 v10 = *(const short8*)(p0 + rs);
    short8 v11 = *(const short8*)(p0 + rs + C);
    #pragma unroll
    for (int e = 0; e < 8; ++e) {
      float f0 = bf2f((unsigned short)v00[e]), f1 = bf2f((unsigned short)v01[e]);
      float f2 = bf2f((unsigned short)v10[e]), f3 = bf2f((unsigned short)v11[e]);
      float mx = fmaxf(fmaxf(f0, f1), fmaxf(f2, f3));
      unsigned short uu;
      if (mx == f0) uu = (unsigned short)v00[e];
      else if (mx == f1) uu = (unsigned short)v01[e];
      else if (mx == f2) uu = (unsigned short)v10[e];
      else uu = (unsigned short)v11[e];
      res[e] = (short)uu;
    }
  }
  *(short8*)(out + (((long)b * H2P + yp) * W2P + xp) * C + c8 * 8) = res;
}

// ---------------- merged weight transposes: fp32 [K][N] -> bf16 [N][K], 9 at once ----------------
struct TAll {
  const float* src[9];
  unsigned short* dst[9];
  int K[9];
  int N[9];
};
__global__ __launch_bounds__(256) void transpose_multi(TAll P) {
  const int z = blockIdx.z;
  const int K = P.K[z], N = P.N[z];
  const int k0 = blockIdx.x * 32, n0 = blockIdx.y * 32;
  if (k0 >= K || n0 >= N) return;
  __shared__ float T[32][33];
  const float* in = P.src[z];
  unsigned short* out = P.dst[z];
  const int tid = threadIdx.x;
  const int r = tid >> 3, c4 = (tid & 7) * 4;
  if (n0 + 32 <= N) {
    float4 v = *(const float4*)(in + (long)(k0 + r) * N + n0 + c4);
    T[r][c4 + 0] = v.x; T[r][c4 + 1] = v.y; T[r][c4 + 2] = v.z; T[r][c4 + 3] = v.w;
  } else {
    #pragma unroll
    for (int i = 0; i < 4; ++i) {
      int col = n0 + c4 + i;
      T[r][c4 + i] = (col < N) ? in[(long)(k0 + r) * N + col] : 0.f;
    }
  }
  __syncthreads();
  if (n0 + r < N) {
    us4 o;
    #pragma unroll
    for (int i = 0; i < 4; ++i) o[i] = f2bf(T[c4 + i][r]);
    *(us4*)(out + (long)(n0 + r) * K + k0 + c4) = o;
  }
}

// ---------------- zero init: P1/C4 HALOS only + bar/hs slabs ----------------
// P1: [64][18][130][64] zero y in {0,17} and x in {0,129}
// C4: [64][6][34][256]  zero y in {0,5}  and x in {0,33}
__global__ __launch_bounds__(256) void zero_init(
    unsigned short* __restrict__ P1, unsigned short* __restrict__ C4p,
    float* __restrict__ f0, long n0, float* __restrict__ f1, long n1) {
  const long i0 = (long)blockIdx.x * 256 + threadIdx.x;
  const long st = (long)gridDim.x * 256;
  short8 z = {};
  // P1 top/bottom rows: 64 b x 2 rows x 1040 short8-units (row = 130*64 = 8320 ush)
  for (long j = i0; j < 64L * 2 * 1040; j += st) {
    int b = (int)(j / 2080); long r = j % 2080;
    int y = (r >= 1040) ? 17 : 0; long c = r % 1040;
    *(short8*)(P1 + ((long)b * 18 + y) * 8320 + c * 8) = z;
  }
  // P1 side cols: 64 b x 16 y x 2 x x 8 units (col cell = 64 ush)
  for (long j = i0; j < 64L * 16 * 2 * 8; j += st) {
    int b = (int)(j >> 8); long r = j & 255;
    int y = 1 + (int)(r >> 4); long r2 = r & 15;
    int x = (r2 >= 8) ? 129 : 0; long c = r2 & 7;
    *(short8*)(P1 + (((long)b * 18 + y) * 130 + x) * 64 + c * 8) = z;
  }
  // C4 top/bottom rows: 64 b x 2 rows x 1088 units (row = 34*256 = 8704 ush)
  for (long j = i0; j < 64L * 2 * 1088; j += st) {
    int b = (int)(j / 2176); long r = j % 2176;
    int y = (r >= 1088) ? 5 : 0; long c = r % 1088;
    *(short8*)(C4p + ((long)b * 6 + y) * 8704 + c * 8) = z;
  }
  // C4 side cols: 64 b x 4 y x 2 x x 32 units (col cell = 256 ush)
  for (long j = i0; j < 64L * 4 * 2 * 32; j += st) {
    int b = (int)(j >> 8); long r = j & 255;
    int y = 1 + (int)(r >> 6); long r2 = r & 63;
    int x = (r2 >= 32) ? 33 : 0; long c = r2 & 31;
    *(short8*)(C4p + (((long)b * 6 + y) * 34 + x) * 256 + c * 8) = z;
  }
  for (long j = i0; j < n0; j += st) f0[j] = 0.f;
  for (long j = i0; j < n1; j += st) f1[j] = 0.f;
}

// ---------------- 2-phase pipelined implicit-GEMM conv, XCD-swizzled 1-D grid ----------------
template<int CIN, int COUT, int H, int W, int OUTPAD, int NBM, int NBN>
__global__ __launch_bounds__(256) void conv_mfma128(
    const unsigned short* __restrict__ act, const unsigned short* __restrict__ wT,
    const float* __restrict__ bias, const float* __restrict__ sc,
    const float* __restrict__ of, const float* __restrict__ mn,
    const float* __restrict__ vr, unsigned short* __restrict__ out) {
  constexpr int K9 = 9 * CIN;
  constexpr int HW = H * W;
  constexpr int WP = W + 2;
  constexpr int NK = K9 / 32;
  constexpr int NWG = NBM * NBN;
  constexpr int CSH = (CIN == 64) ? 1 : (CIN == 128) ? 2 : 3;
  constexpr int CMSK = (1 << CSH) - 1;
  __shared__ unsigned short As[2][4096];
  __shared__ unsigned short Bs[2][4096];
  const int tid = threadIdx.x;
  const int lane = tid & 63, wave = tid >> 6;
  const int wzw = blockIdx.x;
  const int logical = (wzw & 7) * (NWG >> 3) + (wzw >> 3);
  const int m0 = (logical % NBM) * 128, n0 = (logical / NBM) * 128;
  const int r0 = tid >> 2, seg = tid & 3;
  const int segp = (seg ^ (r0 & 3)) << 3;
  long pa0, pa1;
  {
    const int m = m0 + r0;
    const int b = m / HW, rem = m % HW;
    const int y = rem / W, x = rem % W;
    pa0 = (((long)b * (H + 2) + y) * WP + x) * CIN + segp;
  }
  {
    const int m = m0 + r0 + 64;
    const int b = m / HW, rem = m % HW;
    const int y = rem / W, x = rem % W;
    pa1 = (((long)b * (H + 2) + y) * WP + x) * CIN + segp;
  }
  const long pb0 = (long)(n0 + r0) * K9 + segp;
  const long pb1 = (long)(n0 + r0 + 64) * K9 + segp;
  const int swz = ((lane >> 4) ^ (lane & 3)) << 3;
  const int arow0 = (wave >> 1) * 64 + (lane & 15);
  const int brow0 = (wave & 1) * 64 + (lane & 15);
  f32x4 acc[4][4] = {};

  auto stage_tile = [&](int ks, int buf) {
    const int tap = ks >> CSH;
    const int cib = (ks & CMSK) << 5;
    const int ty = (tap * 86) >> 8;          // tap/3 for tap<9
    const int tx = tap - ty * 3;
    const long ka = (long)(ty * WP + tx) * CIN + cib;
    const long kb = (long)ks << 5;
    unsigned short* aw = &As[buf][wave * 512];
    unsigned short* bw = &Bs[buf][wave * 512];
    stage16(act + pa0 + ka, aw);
    stage16(act + pa1 + ka, aw + 2048);
    stage16(wT + pb0 + kb, bw);
    stage16(wT + pb1 + kb, bw + 2048);
  };

  stage_tile(0, 0);
  #pragma unroll 1
  for (int ks = 0; ks < NK; ++ks) {
    const int buf = ks & 1;
    if (ks + 1 < NK) {
      stage_tile(ks + 1, buf ^ 1);
      asm volatile("s_waitcnt vmcnt(4)" ::: "memory");
    } else {
      asm volatile("s_waitcnt vmcnt(0)" ::: "memory");
    }
    __builtin_amdgcn_s_barrier();
    __builtin_amdgcn_sched_barrier(0);
    short8 a[4], b[4];
    #pragma unroll
    for (int i = 0; i < 4; ++i)
      a[i] = *(const short8*)(&As[buf][(arow0 + i * 16) * 32 + swz]);
    #pragma unroll
    for (int j = 0; j < 4; ++j)
      b[j] = *(const short8*)(&Bs[buf][(brow0 + j * 16) * 32 + swz]);
    #pragma unroll
    for (int i = 0; i < 4; ++i)
      #pragma unroll
      for (int j = 0; j < 4; ++j)
        acc[i][j] = MFMA16(a[i], b[j], acc[i][j]);
    __builtin_amdgcn_s_barrier();
    __builtin_amdgcn_sched_barrier(0);
  }

  float scl[4], shf[4], bsv[4];
  #pragma unroll
  for (int j = 0; j < 4; ++j) {
    const int col = n0 + (wave & 1) * 64 + j * 16 + (lane & 15);
    scl[j] = sc[col] * rsqrtf(vr[col] + EPSBN);
    shf[j] = of[col] - mn[col] * scl[j];
    bsv[j] = bias[col];
  }
  #pragma unroll
  for (int i = 0; i < 4; ++i) {
    #pragma unroll
    for (int rr = 0; rr < 4; ++rr) {
      const int m = m0 + (wave >> 1) * 64 + i * 16 + (lane >> 4) * 4 + rr;
      const int b = m / HW, rem = m % HW;
      const int y = rem / W, x = rem % W;
      long obase;
      if (OUTPAD) obase = (((long)b * (H + 2) + y + 1) * WP + x + 1) * COUT;
      else        obase = (((long)b * H + y) * W + x) * COUT;
      const int colb = n0 + (wave & 1) * 64 + (lane & 15);
      #pragma unroll
      for (int j = 0; j < 4; ++j) {
        const float v = fmaxf(acc[i][j][rr] + bsv[j], 0.f) * scl[j] + shf[j];
        out[obase + colb + j * 16] = f2bf(v);
      }
    }
  }
}

// ---------------- fused 2-dir 2-phase GEMM, XCD-swizzled: xw = gather(x) @ WiT^T + b ----------------
__global__ __launch_bounds__(256) void gemm_xw2(
    const unsigned short* __restrict__ src,
    const unsigned short* __restrict__ WiTF, const unsigned short* __restrict__ WiTB,
    const float* __restrict__ bF, const float* __restrict__ bB,
    float* __restrict__ xwFp, float* __restrict__ xwBp) {
  __shared__ unsigned short As[2][4096];
  __shared__ unsigned short Bs[2][4096];
  const int rev = blockIdx.z;
  const unsigned short* WiT = rev ? WiTB : WiTF;
  const float* bvec = rev ? bB : bF;
  float* xw = rev ? xwBp : xwFp;
  const int tid = threadIdx.x;
  const int lane = tid & 63, wave = tid >> 6;
  const int wzw = blockIdx.x;                       // 0..255
  const int logical = (wzw & 7) * 32 + (wzw >> 3);  // bijective, chunks of 32/XCD
  const int m0 = (logical & 15) * 128, n0 = (logical >> 4) * 128;
  const int r0 = tid >> 2, seg = tid & 3;
  const int segp = (seg ^ (r0 & 3)) << 3;
  long pa0, pa1;
  {
    const int r = m0 + r0;
    const int t = r >> 6, bb = r & 63;
    const int tt = rev ? 31 - t : t;
    pa0 = (long)bb * 65536 + (long)tt * 2048 + segp;
  }
  {
    const int r = m0 + r0 + 64;
    const int t = r >> 6, bb = r & 63;
    const int tt = rev ? 31 - t : t;
    pa1 = (long)bb * 65536 + (long)tt * 2048 + segp;
  }
  const long pb0 = (long)(n0 + r0) * 2048 + segp;
  const long pb1 = (long)(n0 + r0 + 64) * 2048 + segp;
  const int swz = ((lane >> 4) ^ (lane & 3)) << 3;
  const int arow0 = (wave >> 1) * 64 + (lane & 15);
  const int brow0 = (wave & 1) * 64 + (lane & 15);
  f32x4 acc[4][4] = {};

  auto stage_tile = [&](int ks, int buf) {
    const long k0 = (long)ks << 5;
    unsigned short* aw = &As[buf][wave * 512];
    unsigned short* bw = &Bs[buf][wave * 512];
    stage16(src + pa0 + k0, aw);
    stage16(src + pa1 + k0, aw + 2048);
    stage16(WiT + pb0 + k0, bw);
    stage16(WiT + pb1 + k0, bw + 2048);
  };

  stage_tile(0, 0);
  #pragma unroll 1
  for (int ks = 0; ks < 64; ++ks) {
    const int buf = ks & 1;
    if (ks + 1 < 64) {
      stage_tile(ks + 1, buf ^ 1);
      asm volatile("s_waitcnt vmcnt(4)" ::: "memory");
    } else {
      asm volatile("s_waitcnt vmcnt(0)" ::: "memory");
    }
    __builtin_amdgcn_s_barrier();
    __builtin_amdgcn_sched_barrier(0);
    short8 a[4], b[4];
    #pragma unroll
    for (int i = 0; i < 4; ++i)
      a[i] = *(const short8*)(&As[buf][(arow0 + i * 16) * 32 + swz]);
    #pragma unroll
    for (int j = 0; j < 4; ++j)
      b[j] = *(const short8*)(&Bs[buf][(brow0 + j * 16) * 32 + swz]);
    #pragma unroll
    for (int i = 0; i < 4; ++i)
      #pragma unroll
      for (int j = 0; j < 4; ++j)
        acc[i][j] = MFMA16(a[i], b[j], acc[i][j]);
    __builtin_amdgcn_s_barrier();
    __builtin_amdgcn_sched_barrier(0);
  }

  float bsv[4];
  #pragma unroll
  for (int j = 0; j < 4; ++j)
    bsv[j] = bvec[n0 + (wave & 1) * 64 + j * 16 + (lane & 15)];
  #pragma unroll
  for (int i = 0; i < 4; ++i) {
    #pragma unroll
    for (int rr = 0; rr < 4; ++rr) {
      const int row = m0 + (wave >> 1) * 64 + i * 16 + (lane >> 4) * 4 + rr;
      const int colb = n0 + (wave & 1) * 64 + (lane & 15);
      #pragma unroll
      for (int j = 0; j < 4; ++j)
        xw[(long)row * 2048 + colb + j * 16] = acc[i][j][rr] + bsv[j];
    }
  }
}

// ---------------- persistent bidirectional LSTM (r7 proven barrier: acquire-poll) ----------------
__global__ __launch_bounds__(256) void lstm_persist(
    const unsigned short* __restrict__ WhTF, const unsigned short* __restrict__ WhTB,
    const float* __restrict__ xwF, const float* __restrict__ xwB,
    unsigned short* __restrict__ hsF, unsigned short* __restrict__ hsB,
    int* __restrict__ bar) {
  __shared__ unsigned short Whs[64 * 512];
  __shared__ unsigned short Hs[64 * 512];
  __shared__ float Zs[4 * 64 * 16];
  const int bid = blockIdx.x;
  const int dir = bid >> 5;
  const int nb = bid & 31;
  const int u0 = nb * 16;
  const unsigned short* WhT = dir ? WhTB : WhTF;
  const float* xw = dir ? xwB : xwF;
  unsigned short* hs = dir ? hsB : hsF;
  int* flagbase = bar + dir * 32 * 16;
  int* myflag = flagbase + nb * 16;
  const int tid = threadIdx.x;
  const int lane = tid & 63, wave = tid >> 6;
  const int lr = lane & 15, lk = lane >> 4;
  const int mp = wave >> 1, gp = wave & 1;

  #pragma unroll
  for (int i = 0; i < 16; ++i) {
    const int G = i * 256 + tid;
    const int row = G >> 6, g8 = G & 63;
    const int g = row >> 4, u = row & 15;
    short8 v = *(const short8*)(WhT + ((long)(g * 512 + u0 + u) << 9) + g8 * 8);
    *(short8*)(Whs + row * 512 + ((g8 ^ (row & 7)) << 3)) = v;
  }

  const int prow = tid >> 2;
  const int pu4 = (tid & 3) * 4;
  float c4[4] = {0.f, 0.f, 0.f, 0.f};
  float4 xq[4];
  #pragma unroll
  for (int g = 0; g < 4; ++g)
    xq[g] = *(const float4*)(xw + (long)prow * 2048 + g * 512 + u0 + pu4);

  for (int t = 0; t < 32; ++t) {
    const unsigned short* hsrc = hs + (long)t * 32768;
    #pragma unroll
    for (int i = 0; i < 16; ++i) {
      const int G = i * 256 + tid;
      const int row = G >> 6, g8 = G & 63;
      short8 v = *(const short8*)(hsrc + G * 8);
      *(short8*)(Hs + row * 512 + ((g8 ^ (row & 7)) << 3)) = v;
    }
    __syncthreads();

    f32x4 acc[2][2] = {};
    #pragma unroll
    for (int kk = 0; kk < 16; ++kk) {
      const int sw = ((lk + kk * 4) ^ (lr & 7)) << 3;
      short8 a0 = *(const short8*)(Hs + (mp * 32 + lr) * 512 + sw);
      short8 a1 = *(const short8*)(Hs + (mp * 32 + 16 + lr) * 512 + sw);
      short8 b0 = *(const short8*)(Whs + (gp * 32 + lr) * 512 + sw);
      short8 b1 = *(const short8*)(Whs + (gp * 32 + 16 + lr) * 512 + sw);
      acc[0][0] = MFMA16(a0, b0, acc[0][0]);
      acc[0][1] = MFMA16(a0, b1, acc[0][1]);
      acc[1][0] = MFMA16(a1, b0, acc[1][0]);
      acc[1][1] = MFMA16(a1, b1, acc[1][1]);
    }

    #pragma unroll
    for (int im = 0; im < 2; ++im) {
      const int rowb = (mp * 2 + im) * 16 + lk * 4;
      #pragma unroll
      for (int ig = 0; ig < 2; ++ig) {
        const int g = gp * 2 + ig;
        #pragma unroll
        for (int r = 0; r < 4; ++r)
          Zs[g * 1024 + (rowb + r) * 16 + lr] = acc[im][ig][r];
      }
    }
    __syncthreads();

    {
      float4 zi = *(const float4*)(Zs + tid * 4);
      float4 zf = *(const float4*)(Zs + 1024 + tid * 4);
      float4 zg = *(const float4*)(Zs + 2048 + tid * 4);
      float4 zo = *(const float4*)(Zs + 3072 + tid * 4);
      const float* pzi = (const float*)&zi;
      const float* pzf = (const float*)&zf;
      const float* pzg = (const float*)&zg;
      const float* pzo = (const float*)&zo;
      us4 hv;
      #pragma unroll
      for (int r = 0; r < 4; ++r) {
        float ii = fast_sigmoid(pzi[r] + ((const float*)&xq[0])[r]);
        float ff = fast_sigmoid(pzf[r] + ((const float*)&xq[1])[r]);
        float gg = fast_tanh(pzg[r] + ((const float*)&xq[2])[r]);
        float oo = fast_sigmoid(pzo[r] + ((const float*)&xq[3])[r]);
        c4[r] = ff * c4[r] + ii * gg;
        hv[r] = f2bf(oo * fast_tanh(c4[r]));
      }
      *(us4*)(hs + (long)(t + 1) * 32768 + prow * 512 + u0 + pu4) = hv;
    }

    if (t < 31) {
      float4 xqn[4];
      #pragma unroll
      for (int g = 0; g < 4; ++g)
        xqn[g] = *(const float4*)(xw + (long)((t + 1) * 64 + prow) * 2048 + g * 512 + u0 + pu4);
      __syncthreads();
      if (tid < 64) {
        if (tid == 0)
          __hip_atomic_store(myflag, t + 1, __ATOMIC_RELEASE, __HIP_MEMORY_SCOPE_AGENT);
        int v;
        do {
          v = __hip_atomic_load(flagbase + (tid & 31) * 16,
                                __ATOMIC_ACQUIRE, __HIP_MEMORY_SCOPE_AGENT);
        } while (__any(v < t + 1));
      }
      __syncthreads();
      #pragma unroll
      for (int g = 0; g < 4; ++g) xq[g] = xqn[g];
    }
  }
}

// ---------------- MFMA FC (M=128,N=80,K=1024) + fused log_softmax ----------------
__global__ __launch_bounds__(256) void fc_mfma_ls(
    const unsigned short* __restrict__ hsF, const unsigned short* __restrict__ hsB,
    const unsigned short* __restrict__ WT, const float* __restrict__ bias,
    float* __restrict__ out) {
  __shared__ unsigned short As_[128 * 32];
  __shared__ unsigned short Bs_[80 * 32];
  __shared__ float zbuf[128][81];
  __shared__ float rmax[128];
  __shared__ float rlse[128];
  const int tid = threadIdx.x;
  const int lane = tid & 63, wave = tid >> 6;
  const int m0 = blockIdx.x * 128;
  const int r0 = tid >> 2, seg = tid & 3;
  const int segp = (seg ^ (r0 & 3)) << 3;
  const int swz = ((lane >> 4) ^ (lane & 3)) << 3;
  f32x4 acc[2][5] = {};

  int bA0, tA0, bA1, tA1;
  { int r = m0 + r0;      bA0 = r >> 5; tA0 = r & 31; }
  { int r = m0 + r0 + 64; bA1 = r >> 5; tA1 = r & 31; }

  #pragma unroll 1
  for (int k0 = 0; k0 < 1024; k0 += 32) {
    const unsigned short* src = (k0 < 512) ? hsF : hsB;
    const int koff = k0 & 511;
    stage16(src + (long)(tA0 + 1) * 32768 + bA0 * 512 + koff + segp, As_ + wave * 512);
    stage16(src + (long)(tA1 + 1) * 32768 + bA1 * 512 + koff + segp, As_ + wave * 512 + 2048);
    {
      int G = tid;
      #pragma unroll
      for (int it = 0; it < 2; ++it, G += 256) {
        int rn = G >> 2, sg = G & 3;
        if (rn < 80) {
          short8 v = *(const short8*)(WT + (long)rn * 1024 + k0 + sg * 8);
          *(short8*)(Bs_ + rn * 32 + ((sg ^ (rn & 3)) << 3)) = v;
        }
      }
    }
    __syncthreads();
    short8 a[2], bfrag[5];
    #pragma unroll
    for (int i = 0; i < 2; ++i)
      a[i] = *(const short8*)(As_ + (wave * 32 + i * 16 + (lane & 15)) * 32 + swz);
    #pragma unroll
    for (int j = 0; j < 5; ++j)
      bfrag[j] = *(const short8*)(Bs_ + (j * 16 + (lane & 15)) * 32 + swz);
    #pragma unroll
    for (int i = 0; i < 2; ++i)
      #pragma unroll
      for (int j = 0; j < 5; ++j)
        acc[i][j] = MFMA16(a[i], bfrag[j], acc[i][j]);
    __syncthreads();
  }

  float bsv[5];
  #pragma unroll
  for (int j = 0; j < 5; ++j) bsv[j] = bias[j * 16 + (lane & 15)];
  #pragma unroll
  for (int i = 0; i < 2; ++i)
    #pragma unroll
    for (int j = 0; j < 5; ++j)
      #pragma unroll
      for (int rr = 0; rr < 4; ++rr)
        zbuf[wave * 32 + i * 16 + (lane >> 4) * 4 + rr][j * 16 + (lane & 15)] =
            acc[i][j][rr] + bsv[j];
  __syncthreads();

  if (tid < 128) {
    float mx = -1e30f;
    for (int j = 0; j < 80; ++j) mx = fmaxf(mx, zbuf[tid][j]);
    float s = 0.f;
    for (int j = 0; j < 80; ++j) s += __expf(zbuf[tid][j] - mx);
    rmax[tid] = mx;
    rlse[tid] = logf(s);
  }
  __syncthreads();

  for (int idx = tid; idx < 128 * 80; idx += 256) {
    const int row = idx / 80, j = idx - row * 80;
    out[(long)m0 * 80 + idx] = zbuf[row][j] - rmax[row] - rlse[row];
  }
}

extern "C" void kernel_launch(void* const* d_in, const int* in_sizes, int n_in,
                              void* d_out, int out_size, void* d_ws, size_t ws_size,
                              hipStream_t stream) {
  const float* x  = (const float*)d_in[0];
  const float* k1 = (const float*)d_in[1];  const float* b1 = (const float*)d_in[2];
  const float* s1 = (const float*)d_in[3];  const float* o1 = (const float*)d_in[4];
  const float* m1 = (const float*)d_in[5];  const float* v1 = (const float*)d_in[6];
  const float* k2 = (const float*)d_in[7];  const float* b2 = (const float*)d_in[8];
  const float* s2 = (const float*)d_in[9];  const float* o2 = (const float*)d_in[10];
  const float* m2 = (const float*)d_in[11]; const float* v2 = (const float*)d_in[12];
  const float* k3 = (const float*)d_in[13]; const float* b3 = (const float*)d_in[14];
  const float* s3 = (const float*)d_in[15]; const float* o3 = (const float*)d_in[16];
  const float* m3 = (const float*)d_in[17]; const float* v3 = (const float*)d_in[18];
  const float* k4 = (const float*)d_in[19]; const float* b4 = (const float*)d_in[20];
  const float* s4 = (const float*)d_in[21]; const float* o4 = (const float*)d_in[22];
  const float* m4 = (const float*)d_in[23]; const float* v4 = (const float*)d_in[24];
  const float* k5 = (const float*)d_in[25]; const float* b5 = (const float*)d_in[26];
  const float* s5 = (const float*)d_in[27]; const float* o5 = (const float*)d_in[28];
  const float* m5 = (const float*)d_in[29]; const float* v5 = (const float*)d_in[30];
  const float* fwWi = (const float*)d_in[31];
  const float* fwWh = (const float*)d_in[32];
  const float* fwb  = (const float*)d_in[33];
  const float* bwWi = (const float*)d_in[34];
  const float* bwWh = (const float*)d_in[35];
  const float* bwb  = (const float*)d_in[36];
  const float* fcW  = (const float*)d_in[37];
  const float* fcb  = (const float*)d_in[38];

  char* wsb = (char*)d_ws;
  unsigned short* REG_A = (unsigned short*)(wsb);                  // 33,554,432 B
  unsigned short* REG_P = (unsigned short*)(wsb + 33554432);       // 19,169,280 B
  unsigned short* C4    = (unsigned short*)(wsb + 52723712);       //  6,684,672 B
  unsigned short* wT2   = (unsigned short*)(wsb + 59408384);       //    147,456 B
  unsigned short* wT3   = (unsigned short*)(wsb + 59555840);       //    589,824 B
  unsigned short* wT4   = (unsigned short*)(wsb + 60145664);       //  1,179,648 B
  unsigned short* wT5   = (unsigned short*)(wsb + 61325312);       //  2,359,296 B
  unsigned short* WiTF  = (unsigned short*)(wsb + 63684608);       //  8,388,608 B
  unsigned short* WiTB  = (unsigned short*)(wsb + 72073216);       //  8,388,608 B
  unsigned short* WhTF  = (unsigned short*)(wsb + 80461824);       //  2,097,152 B
  unsigned short* WhTB  = (unsigned short*)(wsb + 82558976);       //  2,097,152 B
  unsigned short* WTfc  = (unsigned short*)(wsb + 84656128);       //    163,840 B
  float* xwF = (float*)(wsb + 84819968);                           // 16,777,216 B
  float* xwB = (float*)(wsb + 101597184);                          // 16,777,216 B
  int*   bar = (int*)(wsb + 118374400);                            //      4,096 B
  unsigned short* hsF = (unsigned short*)(wsb + 118378496);        //  2,162,688 B
  unsigned short* hsB = (unsigned short*)(wsb + 120541184);        //  2,162,688 B

  // zeros: P1/C4 halos + {bar+hsF slab0} + {hsB slab0}
  zero_init<<<1024, 256, 0, stream>>>(
      REG_P, C4,
      (float*)(wsb + 118374400), 17408,
      (float*)(wsb + 120541184), 16384);

  // all weight transposes in one dispatch (incl. FC ragged-N)
  TAll tp;
  tp.src[0] = k2; tp.dst[0] = wT2; tp.K[0] = 576;  tp.N[0] = 128;
  tp.src[1] = k3; tp.dst[1] = wT3; tp.K[1] = 1152; tp.N[1] = 256;
  tp.src[2] = k4; tp.dst[2] = wT4; tp.K[2] = 2304; tp.N[2] = 256;
  tp.src[3] = k5; tp.dst[3] = wT5; tp.K[3] = 2304; tp.N[3] = 512;
  tp.src[4] = fwWi + 4194304; tp.dst[4] = WiTF; tp.K[4] = 2048; tp.N[4] = 2048;
  tp.src[5] = bwWi + 4194304; tp.dst[5] = WiTB; tp.K[5] = 2048; tp.N[5] = 2048;
  tp.src[6] = fwWh + 1048576; tp.dst[6] = WhTF; tp.K[6] = 512;  tp.N[6] = 2048;
  tp.src[7] = bwWh + 1048576; tp.dst[7] = WhTB; tp.K[7] = 512;  tp.N[7] = 2048;
  tp.src[8] = fcW; tp.dst[8] = WTfc; tp.K[8] = 1024; tp.N[8] = 80;
  transpose_multi<<<dim3(72, 64, 9), 256, 0, stream>>>(tp);

  // fused conv1+pool1 -> P1 padded [64,18,130,64]
  conv1_pool<<<1024, 256, 0, stream>>>(x, k1, b1, s1, o1, m1, v1, REG_P);

  // conv2: P1 -> C2 [64,16,128,128]
  conv_mfma128<64, 128, 16, 128, 0, 1024, 1><<<1024, 256, 0, stream>>>(
      REG_P, wT2, b2, s2, o2, m2, v2, REG_A);
  maxpool_pad_vec<128, 8, 64><<<2640, 256, 0, stream>>>(REG_A, REG_P);

  // conv3: P2 -> C3 [64,8,64,256]
  conv_mfma128<128, 256, 8, 64, 0, 256, 2><<<512, 256, 0, stream>>>(
      REG_P, wT3, b3, s3, o3, m3, v3, REG_A);
  maxpool_pad_vec<256, 4, 32><<<1632, 256, 0, stream>>>(REG_A, REG_P);

  // conv4: P3 -> C4 PADDED [64,6,34,256]
  conv_mfma128<256, 256, 4, 32, 1, 64, 2><<<128, 256, 0, stream>>>(
      REG_P, wT4, b4, s4, o4, m4, v4, C4);

  // conv5: C4 -> C5 [64,4,32,512]
  conv_mfma128<256, 512, 4, 32, 0, 64, 4><<<256, 256, 0, stream>>>(
      C4, wT5, b5, s5, o5, m5, v5, REG_A);

  // xw precompute, both directions fused (layer 1 only), XCD-swizzled
  gemm_xw2<<<dim3(256, 1, 2), 256, 0, stream>>>(
      REG_A, WiTF, WiTB, fwb + 2048, bwb + 2048, xwF, xwB);

  // all 32 LSTM steps, both directions, single launch
  lstm_persist<<<64, 256, 0, stream>>>(WhTF, WhTB, xwF, xwB, hsF, hsB, bar);

  // FC + log_softmax
  fc_mfma_ls<<<16, 256, 0, stream>>>(hsF, hsB, WTfc, fcb, (float*)d_out);
}

// Round 12
// 444.485 us; speedup vs baseline: 1.0960x; 1.0449x over previous
//
#include <hip/hip_runtime.h>
#include <hip/hip_bf16.h>
#include <math.h>

#define EPSBN 1e-5f

using short8 = __attribute__((ext_vector_type(8))) short;
using f32x4  = __attribute__((ext_vector_type(4))) float;
using us4    = __attribute__((ext_vector_type(4))) unsigned short;

#define MFMA16(a, b, c) __builtin_amdgcn_mfma_f32_16x16x32_bf16(a, b, c, 0, 0, 0)

__device__ __forceinline__ float bf2f(unsigned short u) {
  unsigned int v = ((unsigned int)u) << 16;
  float f;
  __builtin_memcpy(&f, &v, 4);
  return f;
}
__device__ __forceinline__ unsigned short f2bf(float f) {
  __hip_bfloat16 h = __float2bfloat16(f);
  unsigned short u;
  __builtin_memcpy(&u, &h, 2);
  return u;
}
__device__ __forceinline__ float fast_sigmoid(float z) {
  return __builtin_amdgcn_rcpf(1.f + __expf(-z));
}
__device__ __forceinline__ float fast_tanh(float z) {
  float x2 = fminf(fmaxf(2.f * z, -30.f), 30.f);
  float e = __expf(x2);
  return (e - 1.f) * __builtin_amdgcn_rcpf(e + 1.f);
}
// async global->LDS, 16B per lane, dest = wave-uniform base + lane*16
__device__ __forceinline__ void stage16(const unsigned short* g, unsigned short* l) {
  __builtin_amdgcn_global_load_lds(
      (const __attribute__((address_space(1))) void*)g,
      (__attribute__((address_space(3))) void*)l, 16, 0, 0);
}

// ---------------- fused conv1 (3x3, CIN=1, COUT=64) + BN + 2x2 pool -> padded P1 ----------------
__global__ __launch_bounds__(256) void conv1_pool(
    const float* __restrict__ in, const float* __restrict__ w,
    const float* __restrict__ bias, const float* __restrict__ sc,
    const float* __restrict__ of, const float* __restrict__ mn,
    const float* __restrict__ vr, unsigned short* __restrict__ out) {
  __shared__ float lds[4][258];
  __shared__ unsigned short obuf[128 * 64];
  const int blk = blockIdx.x;
  const int b = blk >> 4, y0 = blk & 15;
  const int tid = threadIdx.x;
  for (int i = tid; i < 4 * 258; i += 256) {
    int row = i / 258, c = i - row * 258;
    int iy = 2 * y0 - 1 + row, xx = c - 1;
    float v = 0.f;
    if ((unsigned)iy < 32u && (unsigned)xx < 256u)
      v = in[((b << 5) + iy) * 256 + xx];
    lds[row][c] = v;
  }
  __syncthreads();
  const int co = tid & 63, xg = tid >> 6;
  float w9[9];
  #pragma unroll
  for (int t = 0; t < 9; ++t) w9[t] = w[t * 64 + co];
  const float scale = sc[co] * rsqrtf(vr[co] + EPSBN);
  const float shift = of[co] - mn[co] * scale;
  const float bs = bias[co];
  for (int px = 0; px < 32; ++px) {
    const int xp = xg * 32 + px;
    float m = -1e30f;
    #pragma unroll
    for (int dy = 0; dy < 2; ++dy) {
      #pragma unroll
      for (int dx = 0; dx < 2; ++dx) {
        const int x = 2 * xp + dx;
        float acc = bs;
        #pragma unroll
        for (int r = 0; r < 3; ++r)
          #pragma unroll
          for (int cc = 0; cc < 3; ++cc)
            acc = fmaf(lds[dy + r][x + cc], w9[r * 3 + cc], acc);
        float v = fmaxf(acc, 0.f) * scale + shift;
        m = fmaxf(m, v);
      }
    }
    obuf[xp * 64 + co] = f2bf(m);
  }
  __syncthreads();
  unsigned short* orow = out + (((long)(b * 18 + y0 + 1) * 130 + 1) << 6);
  for (int i = tid; i < 1024; i += 256)
    *(short8*)(orow + i * 8) = *(const short8*)(obuf + i * 8);
}

// ---------------- merged weight transposes: fp32 [K][N] -> bf16 [N][K], 9 at once ----------------
struct TAll {
  const float* src[9];
  unsigned short* dst[9];
  int K[9];
  int N[9];
};
__global__ __launch_bounds__(256) void transpose_multi(TAll P) {
  const int z = blockIdx.z;
  const int K = P.K[z], N = P.N[z];
  const int k0 = blockIdx.x * 32, n0 = blockIdx.y * 32;
  if (k0 >= K || n0 >= N) return;
  __shared__ float T[32][33];
  const float* in = P.src[z];
  unsigned short* out = P.dst[z];
  const int tid = threadIdx.x;
  const int r = tid >> 3, c4 = (tid & 7) * 4;
  if (n0 + 32 <= N) {
    float4 v = *(const float4*)(in + (long)(k0 + r) * N + n0 + c4);
    T[r][c4 + 0] = v.x; T[r][c4 + 1] = v.y; T[r][c4 + 2] = v.z; T[r][c4 + 3] = v.w;
  } else {
    #pragma unroll
    for (int i = 0; i < 4; ++i) {
      int col = n0 + c4 + i;
      T[r][c4 + i] = (col < N) ? in[(long)(k0 + r) * N + col] : 0.f;
    }
  }
  __syncthreads();
  if (n0 + r < N) {
    us4 o;
    #pragma unroll
    for (int i = 0; i < 4; ++i) o[i] = f2bf(T[c4 + i][r]);
    *(us4*)(out + (long)(n0 + r) * K + k0 + c4) = o;
  }
}

// ---------------- zero halos of 4 padded tensors + float slabs ----------------
struct ZHP {
  unsigned short* p[4];
  int HP[4], WP[4], C[4];
};
__global__ __launch_bounds__(256) void zero_halos(
    ZHP Z, float* __restrict__ f0, long n0, float* __restrict__ f1, long n1) {
  const long i0 = (long)blockIdx.x * 256 + threadIdx.x;
  const long st = (long)gridDim.x * 256;
  short8 z = {};
  #pragma unroll
  for (int t = 0; t < 4; ++t) {
    unsigned short* p = Z.p[t];
    const int HP = Z.HP[t], WP = Z.WP[t], C = Z.C[t];
    const long rc = (long)WP * C / 8;
    const long tot_r = 64L * 2 * rc;
    for (long j = i0; j < tot_r; j += st) {
      long b = j / (2 * rc), r = j % (2 * rc);
      int y = (r >= rc) ? (HP - 1) : 0;
      long c = (r >= rc) ? r - rc : r;
      *(short8*)(p + (((long)b * HP + y) * WP) * C + c * 8) = z;
    }
    const long cc = C / 8;
    const long grp = (long)(HP - 2) * 2 * cc;
    const long tot_c = 64L * grp;
    for (long j = i0; j < tot_c; j += st) {
      long b = j / grp, r = j % grp;
      int y = 1 + (int)(r / (2 * cc));
      long r2 = r % (2 * cc);
      int x = (r2 >= cc) ? (WP - 1) : 0;
      long c = (r2 >= cc) ? r2 - cc : r2;
      *(short8*)(p + (((long)b * HP + y) * WP + x) * C + c * 8) = z;
    }
  }
  for (long j = i0; j < n0; j += st) f0[j] = 0.f;
  for (long j = i0; j < n1; j += st) f1[j] = 0.f;
}

// ---------------- fused conv+BN+relu+2x2pool (conv2/conv3): 2-row x 64-col tiles ----------------
// input padded [64][H+2][W+2][CIN]; output pooled padded [64][H/2+2][W/2+2][COUT]
template<int CIN, int COUT, int H, int W, int NBM, int NBN>
__global__ __launch_bounds__(256) void conv_pool_mfma(
    const unsigned short* __restrict__ act, const unsigned short* __restrict__ wT,
    const float* __restrict__ bias, const float* __restrict__ sc,
    const float* __restrict__ of, const float* __restrict__ mn,
    const float* __restrict__ vr, unsigned short* __restrict__ out) {
  constexpr int K9 = 9 * CIN;
  constexpr int WP = W + 2;
  constexpr int NK = K9 / 32;
  constexpr int NWG = NBM * NBN;
  constexpr int TX = W / 64;
  constexpr int H2 = H / 2;
  constexpr int HPO = H2 + 2, WPO = W / 2 + 2;
  constexpr int CSH = (CIN == 64) ? 1 : (CIN == 128) ? 2 : 3;
  constexpr int CMSK = (1 << CSH) - 1;
  __shared__ unsigned short SM[16384];      // K-loop: As[2][4096]+Bs[2][4096]; epilogue: [128][128]
  unsigned short* As0 = SM;
  unsigned short* Bs0 = SM + 8192;
  const int tid = threadIdx.x;
  const int lane = tid & 63, wave = tid >> 6;
  const int wzw = blockIdx.x;
  const int logical = (wzw & 7) * (NWG >> 3) + (wzw >> 3);
  const int mt = logical % NBM;
  const int n0 = (logical / NBM) * 128;
  const int tx = mt % TX;
  const int t2 = mt / TX;
  const int yh = t2 % H2;
  const int bb = t2 / H2;
  const int r0 = tid >> 2, seg = tid & 3;
  const int segp = (seg ^ (r0 & 3)) << 3;
  const long pa0 = (((long)bb * (H + 2) + 2 * yh) * WP + tx * 64 + r0) * CIN + segp;
  const long pa1 = (((long)bb * (H + 2) + 2 * yh + 1) * WP + tx * 64 + r0) * CIN + segp;
  const long pb0 = (long)(n0 + r0) * K9 + segp;
  const long pb1 = (long)(n0 + r0 + 64) * K9 + segp;
  const int swz = ((lane >> 4) ^ (lane & 3)) << 3;
  const int arow0 = (wave >> 1) * 64 + (lane & 15);
  const int brow0 = (wave & 1) * 64 + (lane & 15);
  f32x4 acc[4][4] = {};

  auto stage_tile = [&](int ks, int buf) {
    const int tap = ks >> CSH;
    const int cib = (ks & CMSK) << 5;
    const int ty = (tap * 86) >> 8;          // tap/3 for tap<9
    const int txp = tap - ty * 3;
    const long ka = (long)(ty * WP + txp) * CIN + cib;
    const long kb = (long)ks << 5;
    unsigned short* aw = As0 + buf * 4096 + wave * 512;
    unsigned short* bw = Bs0 + buf * 4096 + wave * 512;
    stage16(act + pa0 + ka, aw);
    stage16(act + pa1 + ka, aw + 2048);
    stage16(wT + pb0 + kb, bw);
    stage16(wT + pb1 + kb, bw + 2048);
  };

  stage_tile(0, 0);
  #pragma unroll 1
  for (int ks = 0; ks < NK; ++ks) {
    const int buf = ks & 1;
    if (ks + 1 < NK) {
      stage_tile(ks + 1, buf ^ 1);
      asm volatile("s_waitcnt vmcnt(4)" ::: "memory");
    } else {
      asm volatile("s_waitcnt vmcnt(0)" ::: "memory");
    }
    __builtin_amdgcn_s_barrier();
    __builtin_amdgcn_sched_barrier(0);
    short8 a[4], b[4];
    #pragma unroll
    for (int i = 0; i < 4; ++i)
      a[i] = *(const short8*)(As0 + buf * 4096 + (arow0 + i * 16) * 32 + swz);
    #pragma unroll
    for (int j = 0; j < 4; ++j)
      b[j] = *(const short8*)(Bs0 + buf * 4096 + (brow0 + j * 16) * 32 + swz);
    #pragma unroll
    for (int i = 0; i < 4; ++i)
      #pragma unroll
      for (int j = 0; j < 4; ++j)
        acc[i][j] = MFMA16(a[i], b[j], acc[i][j]);
    __builtin_amdgcn_s_barrier();
    __builtin_amdgcn_sched_barrier(0);
  }

  // BN + relu -> SM[128 pixels][128 channels]
  float scl[4], shf[4], bsv[4];
  #pragma unroll
  for (int j = 0; j < 4; ++j) {
    const int col = n0 + (wave & 1) * 64 + j * 16 + (lane & 15);
    scl[j] = sc[col] * rsqrtf(vr[col] + EPSBN);
    shf[j] = of[col] - mn[col] * scl[j];
    bsv[j] = bias[col];
  }
  #pragma unroll
  for (int i = 0; i < 4; ++i) {
    #pragma unroll
    for (int rr = 0; rr < 4; ++rr) {
      const int mrow = (wave >> 1) * 64 + i * 16 + (lane >> 4) * 4 + rr;
      const int collb = (wave & 1) * 64 + (lane & 15);
      #pragma unroll
      for (int j = 0; j < 4; ++j) {
        const float v = fmaxf(acc[i][j][rr] + bsv[j], 0.f) * scl[j] + shf[j];
        SM[mrow * 128 + collb + j * 16] = f2bf(v);
      }
    }
  }
  __syncthreads();

  // pool 2x2: quad q (0..31 = x-pairs), channels cg..cg+15
  const int q = tid >> 3, cg = (tid & 7) * 16;
  short8 p00a = *(const short8*)(SM + (2 * q) * 128 + cg);
  short8 p00b = *(const short8*)(SM + (2 * q) * 128 + cg + 8);
  short8 p01a = *(const short8*)(SM + (2 * q + 1) * 128 + cg);
  short8 p01b = *(const short8*)(SM + (2 * q + 1) * 128 + cg + 8);
  short8 p10a = *(const short8*)(SM + (64 + 2 * q) * 128 + cg);
  short8 p10b = *(const short8*)(SM + (64 + 2 * q) * 128 + cg + 8);
  short8 p11a = *(const short8*)(SM + (64 + 2 * q + 1) * 128 + cg);
  short8 p11b = *(const short8*)(SM + (64 + 2 * q + 1) * 128 + cg + 8);
  short8 oa, ob;
  #pragma unroll
  for (int e = 0; e < 8; ++e) {
    float f0 = bf2f((unsigned short)p00a[e]), f1 = bf2f((unsigned short)p01a[e]);
    float f2 = bf2f((unsigned short)p10a[e]), f3 = bf2f((unsigned short)p11a[e]);
    float mx = fmaxf(fmaxf(f0, f1), fmaxf(f2, f3));
    unsigned short uu;
    if (mx == f0) uu = (unsigned short)p00a[e];
    else if (mx == f1) uu = (unsigned short)p01a[e];
    else if (mx == f2) uu = (unsigned short)p10a[e];
    else uu = (unsigned short)p11a[e];
    oa[e] = (short)uu;
    float g0 = bf2f((unsigned short)p00b[e]), g1 = bf2f((unsigned short)p01b[e]);
    float g2 = bf2f((unsigned short)p10b[e]), g3 = bf2f((unsigned short)p11b[e]);
    float my = fmaxf(fmaxf(g0, g1), fmaxf(g2, g3));
    if (my == g0) uu = (unsigned short)p00b[e];
    else if (my == g1) uu = (unsigned short)p01b[e];
    else if (my == g2) uu = (unsigned short)p10b[e];
    else uu = (unsigned short)p11b[e];
    ob[e] = (short)uu;
  }
  unsigned short* op = out +
      (((long)bb * HPO + 1 + yh) * WPO + 1 + tx * 32 + q) * COUT + n0 + cg;
  *(short8*)op = oa;
  *(short8*)(op + 8) = ob;
}

// ---------------- 2-phase pipelined implicit-GEMM conv (no pool), XCD-swizzled ----------------
template<int CIN, int COUT, int H, int W, int OUTPAD, int NBM, int NBN>
__global__ __launch_bounds__(256) void conv_mfma128(
    const unsigned short* __restrict__ act, const unsigned short* __restrict__ wT,
    const float* __restrict__ bias, const float* __restrict__ sc,
    const float* __restrict__ of, const float* __restrict__ mn,
    const float* __restrict__ vr, unsigned short* __restrict__ out) {
  constexpr int K9 = 9 * CIN;
  constexpr int HW = H * W;
  constexpr int WP = W + 2;
  constexpr int NK = K9 / 32;
  constexpr int NWG = NBM * NBN;
  constexpr int CSH = (CIN == 64) ? 1 : (CIN == 128) ? 2 : 3;
  constexpr int CMSK = (1 << CSH) - 1;
  __shared__ unsigned short As[2][4096];
  __shared__ unsigned short Bs[2][4096];
  const int tid = threadIdx.x;
  const int lane = tid & 63, wave = tid >> 6;
  const int wzw = blockIdx.x;
  const int logical = (wzw & 7) * (NWG >> 3) + (wzw >> 3);
  const int m0 = (logical % NBM) * 128, n0 = (logical / NBM) * 128;
  const int r0 = tid >> 2, seg = tid & 3;
  const int segp = (seg ^ (r0 & 3)) << 3;
  long pa0, pa1;
  {
    const int m = m0 + r0;
    const int b = m / HW, rem = m % HW;
    const int y = rem / W, x = rem % W;
    pa0 = (((long)b * (H + 2) + y) * WP + x) * CIN + segp;
  }
  {
    const int m = m0 + r0 + 64;
    const int b = m / HW, rem = m % HW;
    const int y = rem / W, x = rem % W;
    pa1 = (((long)b * (H + 2) + y) * WP + x) * CIN + segp;
  }
  const long pb0 = (long)(n0 + r0) * K9 + segp;
  const long pb1 = (long)(n0 + r0 + 64) * K9 + segp;
  const int swz = ((lane >> 4) ^ (lane & 3)) << 3;
  const int arow0 = (wave >> 1) * 64 + (lane & 15);
  const int brow0 = (wave & 1) * 64 + (lane & 15);
  f32x4 acc[4][4] = {};

  auto stage_tile = [&](int ks, int buf) {
    const int tap = ks >> CSH;
    const int cib = (ks & CMSK) << 5;
    const int ty = (tap * 86) >> 8;
    const int tx = tap - ty * 3;
    const long ka = (long)(ty * WP + tx) * CIN + cib;
    const long kb = (long)ks << 5;
    unsigned short* aw = &As[buf][wave * 512];
    unsigned short* bw = &Bs[buf][wave * 512];
    stage16(act + pa0 + ka, aw);
    stage16(act + pa1 + ka, aw + 2048);
    stage16(wT + pb0 + kb, bw);
    stage16(wT + pb1 + kb, bw + 2048);
  };

  stage_tile(0, 0);
  #pragma unroll 1
  for (int ks = 0; ks < NK; ++ks) {
    const int buf = ks & 1;
    if (ks + 1 < NK) {
      stage_tile(ks + 1, buf ^ 1);
      asm volatile("s_waitcnt vmcnt(4)" ::: "memory");
    } else {
      asm volatile("s_waitcnt vmcnt(0)" ::: "memory");
    }
    __builtin_amdgcn_s_barrier();
    __builtin_amdgcn_sched_barrier(0);
    short8 a[4], b[4];
    #pragma unroll
    for (int i = 0; i < 4; ++i)
      a[i] = *(const short8*)(&As[buf][(arow0 + i * 16) * 32 + swz]);
    #pragma unroll
    for (int j = 0; j < 4; ++j)
      b[j] = *(const short8*)(&Bs[buf][(brow0 + j * 16) * 32 + swz]);
    #pragma unroll
    for (int i = 0; i < 4; ++i)
      #pragma unroll
      for (int j = 0; j < 4; ++j)
        acc[i][j] = MFMA16(a[i], b[j], acc[i][j]);
    __builtin_amdgcn_s_barrier();
    __builtin_amdgcn_sched_barrier(0);
  }

  float scl[4], shf[4], bsv[4];
  #pragma unroll
  for (int j = 0; j < 4; ++j) {
    const int col = n0 + (wave & 1) * 64 + j * 16 + (lane & 15);
    scl[j] = sc[col] * rsqrtf(vr[col] + EPSBN);
    shf[j] = of[col] - mn[col] * scl[j];
    bsv[j] = bias[col];
  }
  #pragma unroll
  for (int i = 0; i < 4; ++i) {
    #pragma unroll
    for (int rr = 0; rr < 4; ++rr) {
      const int m = m0 + (wave >> 1) * 64 + i * 16 + (lane >> 4) * 4 + rr;
      const int b = m / HW, rem = m % HW;
      const int y = rem / W, x = rem % W;
      long obase;
      if (OUTPAD) obase = (((long)b * (H + 2) + y + 1) * WP + x + 1) * COUT;
      else        obase = (((long)b * H + y) * W + x) * COUT;
      const int colb = n0 + (wave & 1) * 64 + (lane & 15);
      #pragma unroll
      for (int j = 0; j < 4; ++j) {
        const float v = fmaxf(acc[i][j][rr] + bsv[j], 0.f) * scl[j] + shf[j];
        out[obase + colb + j * 16] = f2bf(v);
      }
    }
  }
}

// ---------------- fused 2-dir 2-phase GEMM, XCD-swizzled: xw = gather(x) @ WiT^T + b ----------------
__global__ __launch_bounds__(256) void gemm_xw2(
    const unsigned short* __restrict__ src,
    const unsigned short* __restrict__ WiTF, const unsigned short* __restrict__ WiTB,
    const float* __restrict__ bF, const float* __restrict__ bB,
    float* __restrict__ xwFp, float* __restrict__ xwBp) {
  __shared__ unsigned short As[2][4096];
  __shared__ unsigned short Bs[2][4096];
  const int rev = blockIdx.z;
  const unsigned short* WiT = rev ? WiTB : WiTF;
  const float* bvec = rev ? bB : bF;
  float* xw = rev ? xwBp : xwFp;
  const int tid = threadIdx.x;
  const int lane = tid & 63, wave = tid >> 6;
  const int wzw = blockIdx.x;
  const int logical = (wzw & 7) * 32 + (wzw >> 3);
  const int m0 = (logical & 15) * 128, n0 = (logical >> 4) * 128;
  const int r0 = tid >> 2, seg = tid & 3;
  const int segp = (seg ^ (r0 & 3)) << 3;
  long pa0, pa1;
  {
    const int r = m0 + r0;
    const int t = r >> 6, bb = r & 63;
    const int tt = rev ? 31 - t : t;
    pa0 = (long)bb * 65536 + (long)tt * 2048 + segp;
  }
  {
    const int r = m0 + r0 + 64;
    const int t = r >> 6, bb = r & 63;
    const int tt = rev ? 31 - t : t;
    pa1 = (long)bb * 65536 + (long)tt * 2048 + segp;
  }
  const long pb0 = (long)(n0 + r0) * 2048 + segp;
  const long pb1 = (long)(n0 + r0 + 64) * 2048 + segp;
  const int swz = ((lane >> 4) ^ (lane & 3)) << 3;
  const int arow0 = (wave >> 1) * 64 + (lane & 15);
  const int brow0 = (wave & 1) * 64 + (lane & 15);
  f32x4 acc[4][4] = {};

  auto stage_tile = [&](int ks, int buf) {
    const long k0 = (long)ks << 5;
    unsigned short* aw = &As[buf][wave * 512];
    unsigned short* bw = &Bs[buf][wave * 512];
    stage16(src + pa0 + k0, aw);
    stage16(src + pa1 + k0, aw + 2048);
    stage16(WiT + pb0 + k0, bw);
    stage16(WiT + pb1 + k0, bw + 2048);
  };

  stage_tile(0, 0);
  #pragma unroll 1
  for (int ks = 0; ks < 64; ++ks) {
    const int buf = ks & 1;
    if (ks + 1 < 64) {
      stage_tile(ks + 1, buf ^ 1);
      asm volatile("s_waitcnt vmcnt(4)" ::: "memory");
    } else {
      asm volatile("s_waitcnt vmcnt(0)" ::: "memory");
    }
    __builtin_amdgcn_s_barrier();
    __builtin_amdgcn_sched_barrier(0);
    short8 a[4], b[4];
    #pragma unroll
    for (int i = 0; i < 4; ++i)
      a[i] = *(const short8*)(&As[buf][(arow0 + i * 16) * 32 + swz]);
    #pragma unroll
    for (int j = 0; j < 4; ++j)
      b[j] = *(const short8*)(&Bs[buf][(brow0 + j * 16) * 32 + swz]);
    #pragma unroll
    for (int i = 0; i < 4; ++i)
      #pragma unroll
      for (int j = 0; j < 4; ++j)
        acc[i][j] = MFMA16(a[i], b[j], acc[i][j]);
    __builtin_amdgcn_s_barrier();
    __builtin_amdgcn_sched_barrier(0);
  }

  float bsv[4];
  #pragma unroll
  for (int j = 0; j < 4; ++j)
    bsv[j] = bvec[n0 + (wave & 1) * 64 + j * 16 + (lane & 15)];
  #pragma unroll
  for (int i = 0; i < 4; ++i) {
    #pragma unroll
    for (int rr = 0; rr < 4; ++rr) {
      const int row = m0 + (wave >> 1) * 64 + i * 16 + (lane >> 4) * 4 + rr;
      const int colb = n0 + (wave & 1) * 64 + (lane & 15);
      #pragma unroll
      for (int j = 0; j < 4; ++j)
        xw[(long)row * 2048 + colb + j * 16] = acc[i][j][rr] + bsv[j];
    }
  }
}

// ---------------- persistent bidirectional LSTM (r7 proven barrier: acquire-poll) ----------------
__global__ __launch_bounds__(256) void lstm_persist(
    const unsigned short* __restrict__ WhTF, const unsigned short* __restrict__ WhTB,
    const float* __restrict__ xwF, const float* __restrict__ xwB,
    unsigned short* __restrict__ hsF, unsigned short* __restrict__ hsB,
    int* __restrict__ bar) {
  __shared__ unsigned short Whs[64 * 512];
  __shared__ unsigned short Hs[64 * 512];
  __shared__ float Zs[4 * 64 * 16];
  const int bid = blockIdx.x;
  const int dir = bid >> 5;
  const int nb = bid & 31;
  const int u0 = nb * 16;
  const unsigned short* WhT = dir ? WhTB : WhTF;
  const float* xw = dir ? xwB : xwF;
  unsigned short* hs = dir ? hsB : hsF;
  int* flagbase = bar + dir * 32 * 16;
  int* myflag = flagbase + nb * 16;
  const int tid = threadIdx.x;
  const int lane = tid & 63, wave = tid >> 6;
  const int lr = lane & 15, lk = lane >> 4;
  const int mp = wave >> 1, gp = wave & 1;

  #pragma unroll
  for (int i = 0; i < 16; ++i) {
    const int G = i * 256 + tid;
    const int row = G >> 6, g8 = G & 63;
    const int g = row >> 4, u = row & 15;
    short8 v = *(const short8*)(WhT + ((long)(g * 512 + u0 + u) << 9) + g8 * 8);
    *(short8*)(Whs + row * 512 + ((g8 ^ (row & 7)) << 3)) = v;
  }

  const int prow = tid >> 2;
  const int pu4 = (tid & 3) * 4;
  float c4[4] = {0.f, 0.f, 0.f, 0.f};
  float4 xq[4];
  #pragma unroll
  for (int g = 0; g < 4; ++g)
    xq[g] = *(const float4*)(xw + (long)prow * 2048 + g * 512 + u0 + pu4);

  for (int t = 0; t < 32; ++t) {
    const unsigned short* hsrc = hs + (long)t * 32768;
    #pragma unroll
    for (int i = 0; i < 16; ++i) {
      const int G = i * 256 + tid;
      const int row = G >> 6, g8 = G & 63;
      short8 v = *(const short8*)(hsrc + G * 8);
      *(short8*)(Hs + row * 512 + ((g8 ^ (row & 7)) << 3)) = v;
    }
    __syncthreads();

    f32x4 acc[2][2] = {};
    #pragma unroll
    for (int kk = 0; kk < 16; ++kk) {
      const int sw = ((lk + kk * 4) ^ (lr & 7)) << 3;
      short8 a0 = *(const short8*)(Hs + (mp * 32 + lr) * 512 + sw);
      short8 a1 = *(const short8*)(Hs + (mp * 32 + 16 + lr) * 512 + sw);
      short8 b0 = *(const short8*)(Whs + (gp * 32 + lr) * 512 + sw);
      short8 b1 = *(const short8*)(Whs + (gp * 32 + 16 + lr) * 512 + sw);
      acc[0][0] = MFMA16(a0, b0, acc[0][0]);
      acc[0][1] = MFMA16(a0, b1, acc[0][1]);
      acc[1][0] = MFMA16(a1, b0, acc[1][0]);
      acc[1][1] = MFMA16(a1, b1, acc[1][1]);
    }

    #pragma unroll
    for (int im = 0; im < 2; ++im) {
      const int rowb = (mp * 2 + im) * 16 + lk * 4;
      #pragma unroll
      for (int ig = 0; ig < 2; ++ig) {
        const int g = gp * 2 + ig;
        #pragma unroll
        for (int r = 0; r < 4; ++r)
          Zs[g * 1024 + (rowb + r) * 16 + lr] = acc[im][ig][r];
      }
    }
    __syncthreads();

    {
      float4 zi = *(const float4*)(Zs + tid * 4);
      float4 zf = *(const float4*)(Zs + 1024 + tid * 4);
      float4 zg = *(const float4*)(Zs + 2048 + tid * 4);
      float4 zo = *(const float4*)(Zs + 3072 + tid * 4);
      const float* pzi = (const float*)&zi;
      const float* pzf = (const float*)&zf;
      const float* pzg = (const float*)&zg;
      const float* pzo = (const float*)&zo;
      us4 hv;
      #pragma unroll
      for (int r = 0; r < 4; ++r) {
        float ii = fast_sigmoid(pzi[r] + ((const float*)&xq[0])[r]);
        float ff = fast_sigmoid(pzf[r] + ((const float*)&xq[1])[r]);
        float gg = fast_tanh(pzg[r] + ((const float*)&xq[2])[r]);
        float oo = fast_sigmoid(pzo[r] + ((const float*)&xq[3])[r]);
        c4[r] = ff * c4[r] + ii * gg;
        hv[r] = f2bf(oo * fast_tanh(c4[r]));
      }
      *(us4*)(hs + (long)(t + 1) * 32768 + prow * 512 + u0 + pu4) = hv;
    }

    if (t < 31) {
      float4 xqn[4];
      #pragma unroll
      for (int g = 0; g < 4; ++g)
        xqn[g] = *(const float4*)(xw + (long)((t + 1) * 64 + prow) * 2048 + g * 512 + u0 + pu4);
      __syncthreads();
      if (tid < 64) {
        if (tid == 0)
          __hip_atomic_store(myflag, t + 1, __ATOMIC_RELEASE, __HIP_MEMORY_SCOPE_AGENT);
        int v;
        do {
          v = __hip_atomic_load(flagbase + (tid & 31) * 16,
                                __ATOMIC_ACQUIRE, __HIP_MEMORY_SCOPE_AGENT);
        } while (__any(v < t + 1));
      }
      __syncthreads();
      #pragma unroll
      for (int g = 0; g < 4; ++g) xq[g] = xqn[g];
    }
  }
}

// ---------------- MFMA FC (M=128,N=80,K=1024) + fused log_softmax ----------------
__global__ __launch_bounds__(256) void fc_mfma_ls(
    const unsigned short* __restrict__ hsF, const unsigned short* __restrict__ hsB,
    const unsigned short* __restrict__ WT, const float* __restrict__ bias,
    float* __restrict__ out) {
  __shared__ unsigned short As_[128 * 32];
  __shared__ unsigned short Bs_[80 * 32];
  __shared__ float zbuf[128][81];
  __shared__ float rmax[128];
  __shared__ float rlse[128];
  const int tid = threadIdx.x;
  const int lane = tid & 63, wave = tid >> 6;
  const int m0 = blockIdx.x * 128;
  const int r0 = tid >> 2, seg = tid & 3;
  const int segp = (seg ^ (r0 & 3)) << 3;
  const int swz = ((lane >> 4) ^ (lane & 3)) << 3;
  f32x4 acc[2][5] = {};

  int bA0, tA0, bA1, tA1;
  { int r = m0 + r0;      bA0 = r >> 5; tA0 = r & 31; }
  { int r = m0 + r0 + 64; bA1 = r >> 5; tA1 = r & 31; }

  #pragma unroll 1
  for (int k0 = 0; k0 < 1024; k0 += 32) {
    const unsigned short* src = (k0 < 512) ? hsF : hsB;
    const int koff = k0 & 511;
    stage16(src + (long)(tA0 + 1) * 32768 + bA0 * 512 + koff + segp, As_ + wave * 512);
    stage16(src + (long)(tA1 + 1) * 32768 + bA1 * 512 + koff + segp, As_ + wave * 512 + 2048);
    {
      int G = tid;
      #pragma unroll
      for (int it = 0; it < 2; ++it, G += 256) {
        int rn = G >> 2, sg = G & 3;
        if (rn < 80) {
          short8 v = *(const short8*)(WT + (long)rn * 1024 + k0 + sg * 8);
          *(short8*)(Bs_ + rn * 32 + ((sg ^ (rn & 3)) << 3)) = v;
        }
      }
    }
    __syncthreads();
    short8 a[2], bfrag[5];
    #pragma unroll
    for (int i = 0; i < 2; ++i)
      a[i] = *(const short8*)(As_ + (wave * 32 + i * 16 + (lane & 15)) * 32 + swz);
    #pragma unroll
    for (int j = 0; j < 5; ++j)
      bfrag[j] = *(const short8*)(Bs_ + (j * 16 + (lane & 15)) * 32 + swz);
    #pragma unroll
    for (int i = 0; i < 2; ++i)
      #pragma unroll
      for (int j = 0; j < 5; ++j)
        acc[i][j] = MFMA16(a[i], bfrag[j], acc[i][j]);
    __syncthreads();
  }

  float bsv[5];
  #pragma unroll
  for (int j = 0; j < 5; ++j) bsv[j] = bias[j * 16 + (lane & 15)];
  #pragma unroll
  for (int i = 0; i < 2; ++i)
    #pragma unroll
    for (int j = 0; j < 5; ++j)
      #pragma unroll
      for (int rr = 0; rr < 4; ++rr)
        zbuf[wave * 32 + i * 16 + (lane >> 4) * 4 + rr][j * 16 + (lane & 15)] =
            acc[i][j][rr] + bsv[j];
  __syncthreads();

  if (tid < 128) {
    float mx = -1e30f;
    for (int j = 0; j < 80; ++j) mx = fmaxf(mx, zbuf[tid][j]);
    float s = 0.f;
    for (int j = 0; j < 80; ++j) s += __expf(zbuf[tid][j] - mx);
    rmax[tid] = mx;
    rlse[tid] = logf(s);
  }
  __syncthreads();

  for (int idx = tid; idx < 128 * 80; idx += 256) {
    const int row = idx / 80, j = idx - row * 80;
    out[(long)m0 * 80 + idx] = zbuf[row][j] - rmax[row] - rlse[row];
  }
}

extern "C" void kernel_launch(void* const* d_in, const int* in_sizes, int n_in,
                              void* d_out, int out_size, void* d_ws, size_t ws_size,
                              hipStream_t stream) {
  const float* x  = (const float*)d_in[0];
  const float* k1 = (const float*)d_in[1];  const float* b1 = (const float*)d_in[2];
  const float* s1 = (const float*)d_in[3];  const float* o1 = (const float*)d_in[4];
  const float* m1 = (const float*)d_in[5];  const float* v1 = (const float*)d_in[6];
  const float* k2 = (const float*)d_in[7];  const float* b2 = (const float*)d_in[8];
  const float* s2 = (const float*)d_in[9];  const float* o2 = (const float*)d_in[10];
  const float* m2 = (const float*)d_in[11]; const float* v2 = (const float*)d_in[12];
  const float* k3 = (const float*)d_in[13]; const float* b3 = (const float*)d_in[14];
  const float* s3 = (const float*)d_in[15]; const float* o3 = (const float*)d_in[16];
  const float* m3 = (const float*)d_in[17]; const float* v3 = (const float*)d_in[18];
  const float* k4 = (const float*)d_in[19]; const float* b4 = (const float*)d_in[20];
  const float* s4 = (const float*)d_in[21]; const float* o4 = (const float*)d_in[22];
  const float* m4 = (const float*)d_in[23]; const float* v4 = (const float*)d_in[24];
  const float* k5 = (const float*)d_in[25]; const float* b5 = (const float*)d_in[26];
  const float* s5 = (const float*)d_in[27]; const float* o5 = (const float*)d_in[28];
  const float* m5 = (const float*)d_in[29]; const float* v5 = (const float*)d_in[30];
  const float* fwWi = (const float*)d_in[31];
  const float* fwWh = (const float*)d_in[32];
  const float* fwb  = (const float*)d_in[33];
  const float* bwWi = (const float*)d_in[34];
  const float* bwWh = (const float*)d_in[35];
  const float* bwb  = (const float*)d_in[36];
  const float* fcW  = (const float*)d_in[37];
  const float* fcb  = (const float*)d_in[38];

  char* wsb = (char*)d_ws;
  unsigned short* REG_A = (unsigned short*)(wsb);                  //  8,388,608 B (C5)
  unsigned short* P1    = (unsigned short*)(wsb + 8388608);        // 19,169,280 B
  unsigned short* P2    = (unsigned short*)(wsb + 27557888);       // 10,813,440 B
  unsigned short* P3    = (unsigned short*)(wsb + 38371328);       //  6,684,672 B
  unsigned short* C4    = (unsigned short*)(wsb + 45056000);       //  6,684,672 B
  unsigned short* wT2   = (unsigned short*)(wsb + 51740672);       //    147,456 B
  unsigned short* wT3   = (unsigned short*)(wsb + 51888128);       //    589,824 B
  unsigned short* wT4   = (unsigned short*)(wsb + 52477952);       //  1,179,648 B
  unsigned short* wT5   = (unsigned short*)(wsb + 53657600);       //  2,359,296 B
  unsigned short* WiTF  = (unsigned short*)(wsb + 56016896);       //  8,388,608 B
  unsigned short* WiTB  = (unsigned short*)(wsb + 64405504);       //  8,388,608 B
  unsigned short* WhTF  = (unsigned short*)(wsb + 72794112);       //  2,097,152 B
  unsigned short* WhTB  = (unsigned short*)(wsb + 74891264);       //  2,097,152 B
  unsigned short* WTfc  = (unsigned short*)(wsb + 76988416);       //    163,840 B
  float* xwF = (float*)(wsb + 77152256);                           // 16,777,216 B
  float* xwB = (float*)(wsb + 93929472);                           // 16,777,216 B
  int*   bar = (int*)(wsb + 110706688);                            //      4,096 B
  unsigned short* hsF = (unsigned short*)(wsb + 110710784);        //  2,162,688 B
  unsigned short* hsB = (unsigned short*)(wsb + 112873472);        //  2,162,688 B

  // zero halos of P1/P2/P3/C4 + {bar+hsF slab0} + {hsB slab0}
  ZHP zh;
  zh.p[0] = P1; zh.HP[0] = 18; zh.WP[0] = 130; zh.C[0] = 64;
  zh.p[1] = P2; zh.HP[1] = 10; zh.WP[1] = 66;  zh.C[1] = 128;
  zh.p[2] = P3; zh.HP[2] = 6;  zh.WP[2] = 34;  zh.C[2] = 256;
  zh.p[3] = C4; zh.HP[3] = 6;  zh.WP[3] = 34;  zh.C[3] = 256;
  zero_halos<<<512, 256, 0, stream>>>(
      zh, (float*)(wsb + 110706688), 17408, (float*)(wsb + 112873472), 16384);

  // all weight transposes in one dispatch (incl. FC ragged-N)
  TAll tp;
  tp.src[0] = k2; tp.dst[0] = wT2; tp.K[0] = 576;  tp.N[0] = 128;
  tp.src[1] = k3; tp.dst[1] = wT3; tp.K[1] = 1152; tp.N[1] = 256;
  tp.src[2] = k4; tp.dst[2] = wT4; tp.K[2] = 2304; tp.N[2] = 256;
  tp.src[3] = k5; tp.dst[3] = wT5; tp.K[3] = 2304; tp.N[3] = 512;
  tp.src[4] = fwWi + 4194304; tp.dst[4] = WiTF; tp.K[4] = 2048; tp.N[4] = 2048;
  tp.src[5] = bwWi + 4194304; tp.dst[5] = WiTB; tp.K[5] = 2048; tp.N[5] = 2048;
  tp.src[6] = fwWh + 1048576; tp.dst[6] = WhTF; tp.K[6] = 512;  tp.N[6] = 2048;
  tp.src[7] = bwWh + 1048576; tp.dst[7] = WhTB; tp.K[7] = 512;  tp.N[7] = 2048;
  tp.src[8] = fcW; tp.dst[8] = WTfc; tp.K[8] = 1024; tp.N[8] = 80;
  transpose_multi<<<dim3(72, 64, 9), 256, 0, stream>>>(tp);

  // fused conv1+pool1 -> P1 padded [64,18,130,64]
  conv1_pool<<<1024, 256, 0, stream>>>(x, k1, b1, s1, o1, m1, v1, P1);

  // conv2+pool2: P1 -> P2 padded [64,10,66,128]   (tiles: 2 rows x 64 cols)
  conv_pool_mfma<64, 128, 16, 128, 1024, 1><<<1024, 256, 0, stream>>>(
      P1, wT2, b2, s2, o2, m2, v2, P2);

  // conv3+pool3: P2 -> P3 padded [64,6,34,256]
  conv_pool_mfma<128, 256, 8, 64, 256, 2><<<512, 256, 0, stream>>>(
      P2, wT3, b3, s3, o3, m3, v3, P3);

  // conv4: P3 -> C4 PADDED [64,6,34,256]
  conv_mfma128<256, 256, 4, 32, 1, 64, 2><<<128, 256, 0, stream>>>(
      P3, wT4, b4, s4, o4, m4, v4, C4);

  // conv5: C4 -> C5 [64,4,32,512]
  conv_mfma128<256, 512, 4, 32, 0, 64, 4><<<256, 256, 0, stream>>>(
      C4, wT5, b5, s5, o5, m5, v5, REG_A);

  // xw precompute, both directions fused (layer 1 only), XCD-swizzled
  gemm_xw2<<<dim3(256, 1, 2), 256, 0, stream>>>(
      REG_A, WiTF, WiTB, fwb + 2048, bwb + 2048, xwF, xwB);

  // all 32 LSTM steps, both directions, single launch
  lstm_persist<<<64, 256, 0, stream>>>(WhTF, WhTB, xwF, xwB, hsF, hsB, bar);

  // FC + log_softmax
  fc_mfma_ls<<<16, 256, 0, stream>>>(hsF, hsB, WTfc, fcb, (float*)d_out);
}